// Round 13
// baseline (242.832 us; speedup 1.0000x reference)
//
#include <hip/hip_runtime.h>
#include <hip/hip_bf16.h>
#include <hip/hip_fp16.h>

typedef __hip_bfloat16 bf16;
typedef __attribute__((ext_vector_type(8))) short short8v;
typedef __attribute__((ext_vector_type(4))) short short4v;
typedef __attribute__((ext_vector_type(4))) float f32x4;
typedef __attribute__((ext_vector_type(2))) float f32x2;

__device__ __forceinline__ float b2f(bf16 v){ return __bfloat162float(v); }
__device__ __forceinline__ bf16  f2b(float v){ return __float2bfloat16(v); }
__device__ __forceinline__ float su2f(short s){
    unsigned short us = (unsigned short)s;
    return __bfloat162float(*reinterpret_cast<bf16*>(&us));
}
__device__ __forceinline__ short f2s(float v){
    bf16 b = __float2bfloat16(v);
    return *reinterpret_cast<short*>(&b);
}
__device__ __forceinline__ float ldf(const void* t, size_t i, int isb){
    return isb ? b2f(((const bf16*)t)[i]) : ((const float*)t)[i];
}
// ---- bf8 (e5m2) via the f16 path: e5m2 = high byte of f16 with RNE ----
__device__ __forceinline__ unsigned f2bf8(float f){
    unsigned short h = __half_as_ushort(__float2half(f));
    unsigned lsb = (h >> 8) & 1u, rb = (h >> 7) & 1u, st = (h & 0x7Fu) ? 1u : 0u;
    return ((unsigned)(h >> 8) + (rb & (st | lsb))) & 0xFFu;
}
__device__ __forceinline__ float bf82f(unsigned b){
    return __half2float(__ushort_as_half((unsigned short)(b << 8)));
}

constexpr int Bn = 8, CIN = 384, RESn = 28, Nn = 784, DHn = 1024;
constexpr int AST = 800;   // padded attn/vt K-stride (25*32)

// ---------------------------------------------------- async global->LDS 16B
__device__ __forceinline__ void gload16(const void* g, void* l)
{
    __builtin_amdgcn_global_load_lds(
        (const __attribute__((address_space(1))) void*)g,
        (__attribute__((address_space(3))) void*)l, 16, 0, 0);
}

// -------------------------------------------------- dtype detector (1 thread)
__global__ void k_detect(const unsigned* __restrict__ xw, int* __restrict__ flag)
{
    if (blockIdx.x == 0 && threadIdx.x == 0) {
        int cnt = 0;
        for (int i = 0; i < 256; ++i) {
            unsigned lo = xw[i] & 0xFFFFu;
            int e = (int)((lo >> 7) & 0xFF);
            if (e >= 112 && e <= 132) ++cnt;
        }
        *flag = (cnt >= 128) ? 1 : 0;
    }
}

// -- fused prep: wpack | affine | mixbias | dw-weight transpose (reads d_in raw)
struct PtrArgs { const void* p[26]; };
__global__ __launch_bounds__(256) void k_prep(PtrArgs a, bf16* __restrict__ Wqkv,
                                              float* __restrict__ al, float* __restrict__ be,
                                              float* __restrict__ mb, bf16* __restrict__ Wvlt,
                                              const int* __restrict__ flag)
{
    const int isb = *flag;
    const int tid = threadIdx.x;
    const int role = blockIdx.y;
    if (role == 0) {
        int stride = gridDim.x * 256;
        for (int e = blockIdx.x * 256 + tid; e < 1536 * 384; e += stride) {
            int co = e / 384, k = e % 384;
            const void* src; int lc;
            if (co < 256)      { src = a.p[1]; lc = co; }
            else if (co < 512) { src = a.p[5]; lc = co - 256; }
            else               { src = a.p[9]; lc = co - 512; }
            Wqkv[e] = f2b(ldf(src, (size_t)lc * 384 + k, isb));
        }
    } else if (role == 1) {
        int co = blockIdx.x * 256 + tid;
        if (co < 1536) {
            const void *b_, *s_, *h_; int lc;
            if (co < 256)      { b_ = a.p[2];  s_ = a.p[3];  h_ = a.p[4];  lc = co; }
            else if (co < 512) { b_ = a.p[6];  s_ = a.p[7];  h_ = a.p[8];  lc = co - 256; }
            else               { b_ = a.p[10]; s_ = a.p[11]; h_ = a.p[12]; lc = co - 512; }
            float aa = ldf(s_, lc, isb);
            al[co] = aa;
            be[co] = ldf(b_, lc, isb) * aa + ldf(h_, lc, isb);
        }
    } else if (role == 2) {
        int i = blockIdx.x * 256 + tid;
        if (i < 8 * Nn) {
            int g = i / Nn, p = i % Nn;
            float acc = ldf(a.p[18], g, isb);
            #pragma unroll
            for (int h = 0; h < 8; ++h)
                acc += ldf(a.p[17], g * 8 + h, isb) * ldf(a.p[25], (size_t)h * Nn + p, isb);
            mb[i] = acc;
        }
    } else {
        int e = blockIdx.x * 256 + tid;   // Wvl [1024][9] -> Wvlt [9][1024]
        if (e < 1024 * 9) {
            int c = e / 9, tap = e % 9;
            Wvlt[tap * 1024 + c] = f2b(ldf(a.p[13], e, isb));
        }
    }
}

// ------------------------------------- convert needed tensors -> bf16
struct ConvArgs { const void* src[10]; unsigned long long dstoff[10]; int n[10]; };
__global__ void k_convb_all(ConvArgs a, char* __restrict__ ws, const int* __restrict__ flag)
{
    int i = blockIdx.y;
    int n = a.n[i];
    const void* s = a.src[i];
    bf16* d = (bf16*)(ws + a.dstoff[i]);
    int isb = *flag;
    int stride = gridDim.x * blockDim.x;
    for (int t = blockIdx.x * blockDim.x + threadIdx.x; t < n; t += stride)
        d[t] = isb ? ((const bf16*)s)[t] : f2b(((const float*)s)[t]);
}

// ------------------- expand mb through idx: abfull[g][n][m] (b-independent)
__global__ __launch_bounds__(256) void k_abfull(
    const float* __restrict__ mb, const int* __restrict__ idxs,
    bf16* __restrict__ abfull)
{
    __shared__ float mbs[8][Nn];
    const int tid = threadIdx.x;
    for (int i = tid; i < 8 * Nn; i += 256) ((float*)mbs)[i] = mb[i];
    __syncthreads();
    const int nstart = blockIdx.x * 2;
    for (int n = nstart; n < nstart + 2; ++n) {
        for (int m = tid; m < Nn; m += 256) {
            int id = idxs[(size_t)n * Nn + m];
            #pragma unroll
            for (int g = 0; g < 8; ++g)
                abfull[((size_t)g * Nn + n) * AST + m] = f2b(mbs[g][id]);
        }
    }
}

// ------------- x transpose + inline convert: [b][384][784] -> [b][784][384]
__global__ __launch_bounds__(256) void k_xt(const void* __restrict__ xr, bf16* __restrict__ xt,
                                            const int* __restrict__ flag)
{
    const int isb = *flag;
    __shared__ bf16 t[32][33];
    int b = blockIdx.z, n0 = blockIdx.x * 32, c0 = blockIdx.y * 32;
    int tid = threadIdx.x;
    for (int i = tid; i < 1024; i += 256) {
        int r = i >> 5, c = i & 31;
        int n = n0 + c;
        t[r][c] = (n < Nn) ? f2b(ldf(xr, ((size_t)b * CIN + c0 + r) * Nn + n, isb)) : f2b(0.f);
    }
    __syncthreads();
    for (int i = tid; i < 1024; i += 256) {
        int r = i >> 5, c = i & 31;
        int n = n0 + r;
        if (n < Nn) xt[((size_t)b * Nn + n) * CIN + c0 + c] = t[c][r];
    }
}

// --------------------- v transpose: [n][c] -> [c][n] (stride AST, zero-padded)
__global__ __launch_bounds__(256) void k_vt(const bf16* __restrict__ vbuf, bf16* __restrict__ vt)
{
    __shared__ bf16 t[32][33];
    int b = blockIdx.z, n0 = blockIdx.x * 32, c0 = blockIdx.y * 32;
    int tid = threadIdx.x;
    for (int i = tid; i < 1024; i += 256) {
        int r = i >> 5, c = i & 31;
        int n = n0 + r;
        t[r][c] = (n < Nn) ? vbuf[((size_t)b * Nn + n) * DHn + c0 + c] : f2b(0.f);
    }
    __syncthreads();
    for (int i = tid; i < 1024; i += 256) {
        int r = i >> 5, c = i & 31;
        int n = n0 + c;   // n < 800 always (25*32 grid)
        vt[((size_t)b * DHn + c0 + r) * AST + n] = t[c][r];
    }
}

// ------------------------- colsum_v[b][c] = sum_n v[b][n][c]  (for b2 term)
__global__ __launch_bounds__(256) void k_vcolsum(
    const bf16* __restrict__ vbuf, float* __restrict__ colsum)
{
    __shared__ float red[4][64];
    const int b = blockIdx.y, c0 = blockIdx.x * 64;
    const int t = threadIdx.x, cl = t & 63, part = t >> 6;
    float s = 0.f;
    const int nst = part * 196;
    for (int n = nst; n < nst + 196; ++n)
        s += b2f(vbuf[((size_t)b * Nn + n) * DHn + c0 + cl]);
    red[part][cl] = s;
    __syncthreads();
    if (t < 64)
        colsum[(size_t)b * DHn + c0 + t] = red[0][t] + red[1][t] + red[2][t] + red[3][t];
}

// -------------------- frag-linear staging: 64 rows x 32 k of a K-contig matrix
__device__ __forceinline__ void stage64x32(const bf16* __restrict__ src,
    int row0, int row_lim, int k0, int k_lim, int ld, short* lds, int tid)
{
    int rsub = ((tid >> 6) << 4) | (tid & 15);
    int q    = (tid >> 4) & 3;
    int row = row0 + rsub; row = row < row_lim ? row : row_lim - 1;
    gload16((const short*)src + (size_t)row * ld + k0 + q * 8,
            lds + (size_t)(((rsub >> 4) * 4 + q) * 16 + (rsub & 15)) * 8);
}

// ------------------- generic MFMA core: tile (MI*32) x 128, BK=32, gload_lds
template<int MI>
__device__ __forceinline__ void gemm_core(
    const bf16* __restrict__ A, int lda, int rowsA, int arow0,
    const bf16* __restrict__ B, int ldb, int rowsB, int brow0,
    int K, short* ldsA, short* ldsB, f32x4 (&acc)[MI][4])
{
    const int tid  = threadIdx.x;
    const int lane = tid & 63;
    const int wm   = tid >> 7, wn = (tid >> 6) & 1;
    const short8v* A8 = (const short8v*)ldsA;
    const short8v* B8 = (const short8v*)ldsB;

    for (int k0 = 0; k0 < K; k0 += 32) {
        __syncthreads();
        #pragma unroll
        for (int c = 0; c < MI / 2; ++c)
            stage64x32(A, arow0 + c * 64, rowsA, k0, K, lda, ldsA + c * 2048, tid);
        #pragma unroll
        for (int c = 0; c < 2; ++c)
            stage64x32(B, brow0 + c * 64, rowsB, k0, K, ldb, ldsB + c * 2048, tid);
        __syncthreads();
        short8v a[MI], bb[4];
        #pragma unroll
        for (int i = 0; i < MI; ++i) a[i] = A8[(wm * MI + i) * 64 + lane];
        #pragma unroll
        for (int j = 0; j < 4; ++j) bb[j] = B8[(wn * 4 + j) * 64 + lane];
        #pragma unroll
        for (int i = 0; i < MI; ++i)
            #pragma unroll
            for (int j = 0; j < 4; ++j)
                acc[i][j] = __builtin_amdgcn_mfma_f32_16x16x32_bf16(a[i], bb[j], acc[i][j], 0, 0, 0);
    }
}

#define EPI_COORDS(MI)                                      \
    const int tid  = threadIdx.x;                           \
    const int lane = tid & 63;                              \
    const int wm   = tid >> 7, wn = (tid >> 6) & 1;         \
    const int rq   = lane >> 4, cl = lane & 15; (void)rq;

// --------------------------------------------- q/k/v projection + BN (MFMA)
__global__ __launch_bounds__(256) void k_proj_m(
    const bf16* __restrict__ xt, const bf16* __restrict__ Wqkv,
    const float* __restrict__ al, const float* __restrict__ be,
    bf16* __restrict__ qbuf, bf16* __restrict__ kbuf, bf16* __restrict__ vbuf)
{
    __shared__ short ldsA[4096], ldsB[4096];
    const int n0 = blockIdx.x * 128, co0 = blockIdx.y * 128;
    const int b = blockIdx.z;
    f32x4 acc[4][4] = {};
    gemm_core<4>(xt + (size_t)b * Nn * CIN, CIN, Nn, n0,
                 Wqkv, CIN, 1536, co0, CIN, ldsA, ldsB, acc);
    EPI_COORDS(4)
    #pragma unroll
    for (int i = 0; i < 4; ++i)
        #pragma unroll
        for (int j = 0; j < 4; ++j) {
            int co = co0 + (wn * 4 + j) * 16 + cl;
            float a_ = al[co], bb_ = be[co];
            int nb = n0 + (wm * 4 + i) * 16 + rq * 4;
            #pragma unroll
            for (int r = 0; r < 4; ++r) {
                int n = nb + r;
                if (n >= Nn) continue;
                float y = a_ * acc[i][j][r] + bb_;
                if (co < 256)      qbuf[((size_t)b * Nn + n) * 256 + co]       = f2b(y);
                else if (co < 512) kbuf[((size_t)b * Nn + n) * 256 + (co-256)] = f2b(y);
                else               vbuf[((size_t)b * Nn + n) * DHn + (co-512)] = f2b(y);
            }
        }
}

// ----------------------- raw per-head logits: qk[h][n][m], K=32 (no mix/bias)
__global__ __launch_bounds__(256) void k_logits_raw(
    const bf16* __restrict__ qbuf, const bf16* __restrict__ kbuf,
    bf16* __restrict__ attn, int bi0)
{
    __shared__ short ldsA[4096], ldsB[4096];
    const int n0 = blockIdx.x * 128, m0 = blockIdx.y * 128;
    const int z = blockIdx.z, h = z & 7, bloc = z >> 3, b = bi0 + bloc;
    f32x4 acc[4][4] = {};
    gemm_core<4>(qbuf + (size_t)b * Nn * 256 + h * 32, 256, Nn, n0,
                 kbuf + (size_t)b * Nn * 256 + h * 32, 256, Nn, m0,
                 32, ldsA, ldsB, acc);
    bf16* arow = attn + (size_t)(bloc * 8 + h) * Nn * AST;
    EPI_COORDS(4)
    #pragma unroll
    for (int i = 0; i < 4; ++i)
        #pragma unroll
        for (int j = 0; j < 4; ++j) {
            int m = m0 + (wn * 4 + j) * 16 + cl;
            if (m >= Nn) continue;
            int nb = n0 + (wm * 4 + i) * 16 + rq * 4;
            #pragma unroll
            for (int r = 0; r < 4; ++r) {
                int n = nb + r;
                if (n < Nn) arow[(size_t)n * AST + m] = f2b(acc[i][j][r]);
            }
        }
}

// --- fused: th1 mix (+abfull) + softmax (no-max) + th2 mix (NO b2) -> bf8 P2
__global__ __launch_bounds__(256) void k_softmax_mix(
    const bf16* __restrict__ attn_all, unsigned char* __restrict__ p2_all,
    const bf16* __restrict__ abfull,
    const bf16* __restrict__ W1, const bf16* __restrict__ W2)
{
    const int n = blockIdx.x, bloc = blockIdx.y;
    const int tid = threadIdx.x;
    const bf16* base = attn_all + (size_t)bloc * 8 * Nn * AST;
    unsigned char* p2b = p2_all + (size_t)bloc * 8 * Nn * AST;
    __shared__ float w1s[64], w2s[64], lis[8], wred[4][8];
    if (tid < 64) { w1s[tid] = b2f(W1[tid]) * 0.17677669529663687f; w2s[tid] = b2f(W2[tid]); }
    __syncthreads();

    const bool live = tid < 196;
    const int m0 = (live ? tid : 195) * 4;

    f32x2 raw2[8][2];
    #pragma unroll
    for (int h = 0; h < 8; ++h) {
        short4v v = *(const short4v*)(base + ((size_t)h * Nn + n) * AST + m0);
        raw2[h][0] = f32x2{su2f(v[0]), su2f(v[1])};
        raw2[h][1] = f32x2{su2f(v[2]), su2f(v[3])};
    }

    float out[8][4];
    #pragma unroll
    for (int g = 0; g < 8; ++g) {
        short4v bv = *(const short4v*)(abfull + ((size_t)g * Nn + n) * AST + m0);
        f32x2 a0 = {su2f(bv[0]), su2f(bv[1])};
        f32x2 a1 = {su2f(bv[2]), su2f(bv[3])};
        #pragma unroll
        for (int h = 0; h < 8; ++h) {
            float w = w1s[g * 8 + h];
            f32x2 wv = {w, w};
            a0 += raw2[h][0] * wv;
            a1 += raw2[h][1] * wv;
        }
        out[g][0] = __expf(fminf(a0[0], 60.f));
        out[g][1] = __expf(fminf(a0[1], 60.f));
        out[g][2] = __expf(fminf(a1[0], 60.f));
        out[g][3] = __expf(fminf(a1[1], 60.f));
        float s = live ? (out[g][0] + out[g][1]) + (out[g][2] + out[g][3]) : 0.f;
        #pragma unroll
        for (int sh = 32; sh > 0; sh >>= 1) s += __shfl_xor(s, sh, 64);
        if ((tid & 63) == 0) wred[tid >> 6][g] = s;
    }
    __syncthreads();
    if (tid < 8)
        lis[tid] = 1.f / (wred[0][tid] + wred[1][tid] + wred[2][tid] + wred[3][tid]);
    __syncthreads();

    f32x2 p2[8][2];
    #pragma unroll
    for (int h = 0; h < 8; ++h) {
        float lh = lis[h];
        p2[h][0] = f32x2{out[h][0] * lh, out[h][1] * lh};
        p2[h][1] = f32x2{out[h][2] * lh, out[h][3] * lh};
    }
    if (live) {
        #pragma unroll
        for (int g = 0; g < 8; ++g) {
            f32x2 acc0 = {0.f, 0.f};
            f32x2 acc1 = {0.f, 0.f};
            #pragma unroll
            for (int h = 0; h < 8; ++h) {
                float w = w2s[g * 8 + h];
                f32x2 wv = {w, w};
                acc0 += p2[h][0] * wv;
                acc1 += p2[h][1] * wv;
            }
            unsigned u = f2bf8(acc0[0]) | (f2bf8(acc0[1]) << 8)
                       | (f2bf8(acc1[0]) << 16) | (f2bf8(acc1[1]) << 24);
            *(unsigned*)(p2b + ((size_t)g * Nn + n) * AST + m0) = u;
        }
    }
}

// ------- PV: obuf[b][n][c] = P2mix(bf8) . v  + b2[g]*colsum_v  (MFMA bf16)
__global__ __launch_bounds__(256) void k_pv_m(
    const unsigned char* __restrict__ p2, const bf16* __restrict__ vt,
    const bf16* __restrict__ b2v, const float* __restrict__ colsum,
    bf16* __restrict__ obuf, int bi0)
{
    __shared__ short ldsA[2048], ldsB[4096];
    const int tid = threadIdx.x;
    const int n0 = blockIdx.x * 64;
    const int z = blockIdx.z, g = z & 7, bloc = z >> 3, b = bi0 + bloc;
    const unsigned char* Ap = p2 + (size_t)(bloc * 8 + g) * Nn * AST;
    const bf16* Bv = vt + ((size_t)b * DHn + g * 128) * AST;
    const int lane = tid & 63;
    const int wm = tid >> 7, wn = (tid >> 6) & 1;
    const int rsub = ((tid >> 6) << 4) | (tid & 15);
    const int q = (tid >> 4) & 3;
    const short8v* A8 = (const short8v*)ldsA;
    const short8v* B8 = (const short8v*)ldsB;
    f32x4 acc[2][4] = {};

    for (int k0 = 0; k0 < AST; k0 += 32) {
        __syncthreads();
        {   // A stage: load 8 bf8 bytes, decode -> bf16 frag slot
            int row = n0 + rsub; row = row < Nn ? row : Nn - 1;
            const unsigned char* src = Ap + (size_t)row * AST + k0 + q * 8;
            unsigned lo = *(const unsigned*)src;
            unsigned hi = *(const unsigned*)(src + 4);
            short8v o;
            #pragma unroll
            for (int j = 0; j < 4; ++j) {
                o[j]     = f2s(bf82f((lo >> (8 * j)) & 0xFFu));
                o[4 + j] = f2s(bf82f((hi >> (8 * j)) & 0xFFu));
            }
            ((short8v*)ldsA)[((rsub >> 4) * 4 + q) * 16 + (rsub & 15)] = o;
        }
        stage64x32(Bv, 0,  128, k0, AST, AST, ldsB, tid);
        stage64x32(Bv, 64, 128, k0, AST, AST, ldsB + 2048, tid);
        __syncthreads();
        short8v a[2], bb[4];
        #pragma unroll
        for (int i = 0; i < 2; ++i) a[i] = A8[(wm * 2 + i) * 64 + lane];
        #pragma unroll
        for (int j = 0; j < 4; ++j) bb[j] = B8[(wn * 4 + j) * 64 + lane];
        #pragma unroll
        for (int i = 0; i < 2; ++i)
            #pragma unroll
            for (int j = 0; j < 4; ++j)
                acc[i][j] = __builtin_amdgcn_mfma_f32_16x16x32_bf16(a[i], bb[j], acc[i][j], 0, 0, 0);
    }

    bf16* ob = obuf + (size_t)b * Nn * DHn + g * 128;
    const float b2g = b2f(b2v[g]);
    const int rq = lane >> 4, cl = lane & 15;
    #pragma unroll
    for (int i = 0; i < 2; ++i)
        #pragma unroll
        for (int j = 0; j < 4; ++j) {
            int d = (wn * 4 + j) * 16 + cl;
            float cs = b2g * colsum[(size_t)b * DHn + g * 128 + d];
            int nb = n0 + (wm * 2 + i) * 16 + rq * 4;
            #pragma unroll
            for (int r = 0; r < 4; ++r) {
                int n = nb + r;
                if (n < Nn) ob[(size_t)n * DHn + d] = f2b(acc[i][j][r] + cs);
            }
        }
}

// ---- depthwise conv+BN, ADDS into obuf (o += vl), fully vectorized weights
__global__ __launch_bounds__(256) void k_dwconv_add(
    const bf16* __restrict__ vbuf, const bf16* __restrict__ Wvlt,
    const bf16* __restrict__ bvl, const bf16* __restrict__ vls, const bf16* __restrict__ vlb,
    bf16* __restrict__ obuf)
{
    const int t = threadIdx.x;
    const int n = blockIdx.y * 2 + (t >> 7);
    const int bi = blockIdx.z;
    const int c0 = (t & 127) * 8;
    const int h = n / RESn, w = n % RESn;
    float acc[8] = {};
    #pragma unroll
    for (int dh = -1; dh <= 1; ++dh)
        #pragma unroll
        for (int dw = -1; dw <= 1; ++dw) {
            int hh = h + dh, ww = w + dw;
            if (hh < 0 || hh >= RESn || ww < 0 || ww >= RESn) continue;
            int widx = (dh + 1) * 3 + (dw + 1);
            short8v wv = *(const short8v*)&Wvlt[widx * 1024 + c0];
            short8v v  = *(const short8v*)&vbuf[((size_t)bi * Nn + hh * RESn + ww) * DHn + c0];
            #pragma unroll
            for (int u = 0; u < 8; ++u)
                acc[u] += su2f(wv[u]) * su2f(v[u]);
        }
    short8v bv = *(const short8v*)&bvl[c0];
    short8v sv = *(const short8v*)&vls[c0];
    short8v hv = *(const short8v*)&vlb[c0];
    size_t off = ((size_t)bi * Nn + n) * DHn + c0;
    short8v ov = *(short8v*)&obuf[off];
    short8v res;
    #pragma unroll
    for (int u = 0; u < 8; ++u) {
        float vl = su2f(sv[u]) * (acc[u] + su2f(bv[u])) + su2f(hv[u]);
        res[u] = f2s(su2f(ov[u]) + vl);
    }
    *(short8v*)&obuf[off] = res;
}

// --------------------------------------------- output projection + BN (MFMA)
__global__ __launch_bounds__(256) void k_outproj_m(
    const bf16* __restrict__ Wp, const bf16* __restrict__ obuf,
    const bf16* __restrict__ bp, const bf16* __restrict__ ps, const bf16* __restrict__ pb,
    void* __restrict__ outv, const int* __restrict__ flag)
{
    __shared__ short ldsA[2048], ldsB[4096];
    const int n0 = blockIdx.x * 128, oc0 = blockIdx.y * 64;
    const int b = blockIdx.z;
    f32x4 acc[2][4] = {};
    gemm_core<2>(Wp, DHn, 384, oc0,
                 obuf + (size_t)b * Nn * DHn, DHn, Nn, n0,
                 DHn, ldsA, ldsB, acc);
    const int isb = *flag;
    EPI_COORDS(2)
    #pragma unroll
    for (int i = 0; i < 2; ++i)
        #pragma unroll
        for (int j = 0; j < 4; ++j) {
            int n = n0 + (wn * 4 + j) * 16 + cl;
            if (n >= Nn) continue;
            int ocb = oc0 + (wm * 2 + i) * 16 + rq * 4;
            #pragma unroll
            for (int r = 0; r < 4; ++r) {
                int oc = ocb + r;
                float a_ = b2f(ps[oc]);
                float be_ = b2f(bp[oc]) * a_ + b2f(pb[oc]);
                float y = a_ * acc[i][j][r] + be_;
                size_t idx = ((size_t)b * CIN + oc) * Nn + n;
                if (isb) ((bf16*)outv)[idx] = f2b(y);
                else     ((float*)outv)[idx] = y;
            }
        }
}

extern "C" void kernel_launch(void* const* d_in, const int* in_sizes, int n_in,
                              void* d_out, int out_size, void* d_ws, size_t ws_size,
                              hipStream_t stream)
{
    char* ws = (char*)d_ws;
    auto align256 = [](size_t v) { return (v + 255) & ~(size_t)255; };

    size_t off = 0;
    size_t off_flag = off;            off = align256(off + 4);
    size_t p_off[26];
    for (int i = 0; i < 26; ++i) { p_off[i] = off; off = align256(off + (size_t)in_sizes[i] * 2); }
    size_t off_mb   = off; off = align256(off + (size_t)8 * Nn * 4);
    size_t off_ab   = off; off = align256(off + (size_t)8 * Nn * AST * 2);
    size_t off_q    = off; off = align256(off + (size_t)Bn * Nn * 256 * 2);
    size_t off_k    = off; off = align256(off + (size_t)Bn * Nn * 256 * 2);
    size_t off_v    = off; off = align256(off + (size_t)Bn * Nn * DHn * 2);
    size_t off_vt   = off; off = align256(off + (size_t)Bn * DHn * AST * 2);
    size_t off_o    = off; off = align256(off + (size_t)Bn * Nn * DHn * 2);
    size_t off_xt   = off; off = align256(off + (size_t)Bn * Nn * CIN * 2);
    size_t off_wqkv = off; off = align256(off + (size_t)1536 * CIN * 2);
    size_t off_al   = off; off = align256(off + (size_t)1536 * 4);
    size_t off_be   = off; off = align256(off + (size_t)1536 * 4);
    size_t off_wvlt = off; off = align256(off + (size_t)9 * 1024 * 2);
    size_t off_cs   = off; off = align256(off + (size_t)Bn * DHn * 4);
    size_t base = off;

    const size_t attn_per_b = (size_t)8 * Nn * AST * 2;  // S bf16
    const size_t p2_per_b   = (size_t)8 * Nn * AST;      // P2 bf8
    int GB = 0;
    const int cand[4] = {8, 4, 2, 1};
    for (int ci = 0; ci < 4; ++ci) {
        if (base + (size_t)cand[ci] * (attn_per_b + p2_per_b) + 512 <= ws_size) { GB = cand[ci]; break; }
    }
    if (!GB) return; // ws too small -> zeros out (diagnostic absmax ~17.4)

    size_t off_attn = base;
    size_t off_p2   = align256(off_attn + (size_t)GB * attn_per_b);

    int*  flag = (int*)(ws + off_flag);
    bf16* Pb[26];
    for (int i = 0; i < 26; ++i) Pb[i] = (bf16*)(ws + p_off[i]);
    float* mb    = (float*)(ws + off_mb);
    bf16* abfull = (bf16*)(ws + off_ab);
    bf16* qbuf  = (bf16*)(ws + off_q);
    bf16* kbuf  = (bf16*)(ws + off_k);
    bf16* vbuf  = (bf16*)(ws + off_v);
    bf16* vt    = (bf16*)(ws + off_vt);
    bf16* obuf  = (bf16*)(ws + off_o);
    bf16* xt    = (bf16*)(ws + off_xt);
    bf16* wqkv  = (bf16*)(ws + off_wqkv);
    float* alf  = (float*)(ws + off_al);
    float* bef  = (float*)(ws + off_be);
    bf16* wvlt  = (bf16*)(ws + off_wvlt);
    float* csum = (float*)(ws + off_cs);
    bf16* attn  = (bf16*)(ws + off_attn);
    unsigned char* p2b = (unsigned char*)(ws + off_p2);
    const int* idxs = (const int*)d_in[26];

    k_detect<<<1, 64, 0, stream>>>((const unsigned*)d_in[0], flag);

    PtrArgs pa;
    for (int i = 0; i < 26; ++i) pa.p[i] = d_in[i];
    k_prep<<<dim3(288, 4), 256, 0, stream>>>(pa, wqkv, alf, bef, mb, wvlt, flag);

    const int cidx[10] = {14, 15, 16, 17, 19, 20, 21, 22, 23, 24};
    ConvArgs ca;
    for (int i = 0; i < 10; ++i) {
        ca.src[i] = d_in[cidx[i]];
        ca.dstoff[i] = p_off[cidx[i]];
        ca.n[i] = in_sizes[cidx[i]];
    }
    k_convb_all<<<dim3(64, 10), 256, 0, stream>>>(ca, ws, flag);

    bf16 *bvl = Pb[14], *vls = Pb[15], *vlb = Pb[16],
         *W1 = Pb[17], *W2 = Pb[19], *b2v = Pb[20],
         *Wp = Pb[21], *bp = Pb[22], *ps = Pb[23], *pb = Pb[24];

    k_xt<<<dim3(25, 12, 8), 256, 0, stream>>>(d_in[0], xt, flag);
    k_abfull<<<dim3(392), 256, 0, stream>>>(mb, idxs, abfull);

    k_proj_m<<<dim3(7, 12, 8), 256, 0, stream>>>(xt, wqkv, alf, bef, qbuf, kbuf, vbuf);
    k_vt<<<dim3(25, 32, 8), 256, 0, stream>>>(vbuf, vt);
    k_vcolsum<<<dim3(16, 8), 256, 0, stream>>>(vbuf, csum);

    for (int bi0 = 0; bi0 < Bn; bi0 += GB) {
        k_logits_raw<<<dim3(7, 7, GB * 8), 256, 0, stream>>>(qbuf, kbuf, attn, bi0);
        k_softmax_mix<<<dim3(Nn, GB), 256, 0, stream>>>(attn, p2b, abfull, W1, W2);
        k_pv_m<<<dim3(13, 1, GB * 8), 256, 0, stream>>>(p2b, vt, b2v, csum, obuf, bi0);
    }

    k_dwconv_add<<<dim3(1, Nn / 2, 8), 256, 0, stream>>>(vbuf, wvlt, bvl, vls, vlb, obuf);
    k_outproj_m<<<dim3(7, 6, 8), 256, 0, stream>>>(Wp, obuf, bp, ps, pb, d_out, flag);
}

// Round 14
// 235.794 us; speedup vs baseline: 1.0298x; 1.0298x over previous
//
#include <hip/hip_runtime.h>
#include <hip/hip_bf16.h>
#include <hip/hip_fp16.h>

typedef __hip_bfloat16 bf16;
typedef __attribute__((ext_vector_type(8))) short short8v;
typedef __attribute__((ext_vector_type(4))) short short4v;
typedef __attribute__((ext_vector_type(4))) float f32x4;
typedef __attribute__((ext_vector_type(2))) float f32x2;

__device__ __forceinline__ float b2f(bf16 v){ return __bfloat162float(v); }
__device__ __forceinline__ bf16  f2b(float v){ return __float2bfloat16(v); }
__device__ __forceinline__ float su2f(short s){
    unsigned short us = (unsigned short)s;
    return __bfloat162float(*reinterpret_cast<bf16*>(&us));
}
__device__ __forceinline__ short f2s(float v){
    bf16 b = __float2bfloat16(v);
    return *reinterpret_cast<short*>(&b);
}
__device__ __forceinline__ float ldf(const void* t, size_t i, int isb){
    return isb ? b2f(((const bf16*)t)[i]) : ((const float*)t)[i];
}

// ---- bf8 (e5m2) codec: HW cvt_pk if available, else f16-path software RNE ----
__device__ __forceinline__ unsigned f2bf8_sw(float f){
    unsigned short h = __half_as_ushort(__float2half(f));
    unsigned lsb = (h >> 8) & 1u, rb = (h >> 7) & 1u, st = (h & 0x7Fu) ? 1u : 0u;
    return ((unsigned)(h >> 8) + (rb & (st | lsb))) & 0xFFu;
}
__device__ __forceinline__ float bf82f_sw(unsigned b){
    return __half2float(__ushort_as_half((unsigned short)(b << 8)));
}
// pack 4 f32 -> 4 bf8 bytes
__device__ __forceinline__ unsigned pack4_bf8(float a0, float a1, float a2, float a3){
#if __has_builtin(__builtin_amdgcn_cvt_pk_bf8_f32)
    int u = __builtin_amdgcn_cvt_pk_bf8_f32(a0, a1, 0, false);
    u = __builtin_amdgcn_cvt_pk_bf8_f32(a2, a3, u, true);
    return (unsigned)u;
#else
    return f2bf8_sw(a0) | (f2bf8_sw(a1) << 8) | (f2bf8_sw(a2) << 16) | (f2bf8_sw(a3) << 24);
#endif
}
// unpack 4 bf8 bytes -> 4 f32
__device__ __forceinline__ void unpack4_bf8(unsigned u, float* o){
#if __has_builtin(__builtin_amdgcn_cvt_pk_f32_bf8)
    f32x2 lo = __builtin_amdgcn_cvt_pk_f32_bf8((int)u, false);
    f32x2 hi = __builtin_amdgcn_cvt_pk_f32_bf8((int)u, true);
    o[0] = lo[0]; o[1] = lo[1]; o[2] = hi[0]; o[3] = hi[1];
#else
    o[0] = bf82f_sw(u & 0xFFu);         o[1] = bf82f_sw((u >> 8) & 0xFFu);
    o[2] = bf82f_sw((u >> 16) & 0xFFu); o[3] = bf82f_sw((u >> 24) & 0xFFu);
#endif
}

constexpr int Bn = 8, CIN = 384, RESn = 28, Nn = 784, DHn = 1024;
constexpr int AST = 800;   // padded attn/vt K-stride (25*32)

// ---------------------------------------------------- async global->LDS 16B
__device__ __forceinline__ void gload16(const void* g, void* l)
{
    __builtin_amdgcn_global_load_lds(
        (const __attribute__((address_space(1))) void*)g,
        (__attribute__((address_space(3))) void*)l, 16, 0, 0);
}

// -------------------------------------------------- dtype detector (1 thread)
__global__ void k_detect(const unsigned* __restrict__ xw, int* __restrict__ flag)
{
    if (blockIdx.x == 0 && threadIdx.x == 0) {
        int cnt = 0;
        for (int i = 0; i < 256; ++i) {
            unsigned lo = xw[i] & 0xFFFFu;
            int e = (int)((lo >> 7) & 0xFF);
            if (e >= 112 && e <= 132) ++cnt;
        }
        *flag = (cnt >= 128) ? 1 : 0;
    }
}

// -- fused prep: wpack | affine | mixbias | dw-weight transpose (reads d_in raw)
struct PtrArgs { const void* p[26]; };
__global__ __launch_bounds__(256) void k_prep(PtrArgs a, bf16* __restrict__ Wqkv,
                                              float* __restrict__ al, float* __restrict__ be,
                                              float* __restrict__ mb, bf16* __restrict__ Wvlt,
                                              const int* __restrict__ flag)
{
    const int isb = *flag;
    const int tid = threadIdx.x;
    const int role = blockIdx.y;
    if (role == 0) {
        int stride = gridDim.x * 256;
        for (int e = blockIdx.x * 256 + tid; e < 1536 * 384; e += stride) {
            int co = e / 384, k = e % 384;
            const void* src; int lc;
            if (co < 256)      { src = a.p[1]; lc = co; }
            else if (co < 512) { src = a.p[5]; lc = co - 256; }
            else               { src = a.p[9]; lc = co - 512; }
            Wqkv[e] = f2b(ldf(src, (size_t)lc * 384 + k, isb));
        }
    } else if (role == 1) {
        int co = blockIdx.x * 256 + tid;
        if (co < 1536) {
            const void *b_, *s_, *h_; int lc;
            if (co < 256)      { b_ = a.p[2];  s_ = a.p[3];  h_ = a.p[4];  lc = co; }
            else if (co < 512) { b_ = a.p[6];  s_ = a.p[7];  h_ = a.p[8];  lc = co - 256; }
            else               { b_ = a.p[10]; s_ = a.p[11]; h_ = a.p[12]; lc = co - 512; }
            float aa = ldf(s_, lc, isb);
            al[co] = aa;
            be[co] = ldf(b_, lc, isb) * aa + ldf(h_, lc, isb);
        }
    } else if (role == 2) {
        int i = blockIdx.x * 256 + tid;
        if (i < 8 * Nn) {
            int g = i / Nn, p = i % Nn;
            float acc = ldf(a.p[18], g, isb);
            #pragma unroll
            for (int h = 0; h < 8; ++h)
                acc += ldf(a.p[17], g * 8 + h, isb) * ldf(a.p[25], (size_t)h * Nn + p, isb);
            mb[i] = acc;
        }
    } else {
        int e = blockIdx.x * 256 + tid;   // Wvl [1024][9] -> Wvlt [9][1024]
        if (e < 1024 * 9) {
            int c = e / 9, tap = e % 9;
            Wvlt[tap * 1024 + c] = f2b(ldf(a.p[13], e, isb));
        }
    }
}

// ------------------------------------- convert needed tensors -> bf16
struct ConvArgs { const void* src[10]; unsigned long long dstoff[10]; int n[10]; };
__global__ void k_convb_all(ConvArgs a, char* __restrict__ ws, const int* __restrict__ flag)
{
    int i = blockIdx.y;
    int n = a.n[i];
    const void* s = a.src[i];
    bf16* d = (bf16*)(ws + a.dstoff[i]);
    int isb = *flag;
    int stride = gridDim.x * blockDim.x;
    for (int t = blockIdx.x * blockDim.x + threadIdx.x; t < n; t += stride)
        d[t] = isb ? ((const bf16*)s)[t] : f2b(((const float*)s)[t]);
}

// ------------------- expand mb through idx: abfull[g][n][m] (b-independent)
__global__ __launch_bounds__(256) void k_abfull(
    const float* __restrict__ mb, const int* __restrict__ idxs,
    bf16* __restrict__ abfull)
{
    __shared__ float mbs[8][Nn];
    const int tid = threadIdx.x;
    for (int i = tid; i < 8 * Nn; i += 256) ((float*)mbs)[i] = mb[i];
    __syncthreads();
    const int nstart = blockIdx.x * 2;
    for (int n = nstart; n < nstart + 2; ++n) {
        for (int m = tid; m < Nn; m += 256) {
            int id = idxs[(size_t)n * Nn + m];
            #pragma unroll
            for (int g = 0; g < 8; ++g)
                abfull[((size_t)g * Nn + n) * AST + m] = f2b(mbs[g][id]);
        }
    }
}

// ------------- x transpose + inline convert: [b][384][784] -> [b][784][384]
__global__ __launch_bounds__(256) void k_xt(const void* __restrict__ xr, bf16* __restrict__ xt,
                                            const int* __restrict__ flag)
{
    const int isb = *flag;
    __shared__ bf16 t[32][33];
    int b = blockIdx.z, n0 = blockIdx.x * 32, c0 = blockIdx.y * 32;
    int tid = threadIdx.x;
    for (int i = tid; i < 1024; i += 256) {
        int r = i >> 5, c = i & 31;
        int n = n0 + c;
        t[r][c] = (n < Nn) ? f2b(ldf(xr, ((size_t)b * CIN + c0 + r) * Nn + n, isb)) : f2b(0.f);
    }
    __syncthreads();
    for (int i = tid; i < 1024; i += 256) {
        int r = i >> 5, c = i & 31;
        int n = n0 + r;
        if (n < Nn) xt[((size_t)b * Nn + n) * CIN + c0 + c] = t[c][r];
    }
}

// --------------------- v transpose: [n][c] -> [c][n] (stride AST, zero-padded)
__global__ __launch_bounds__(256) void k_vt(const bf16* __restrict__ vbuf, bf16* __restrict__ vt)
{
    __shared__ bf16 t[32][33];
    int b = blockIdx.z, n0 = blockIdx.x * 32, c0 = blockIdx.y * 32;
    int tid = threadIdx.x;
    for (int i = tid; i < 1024; i += 256) {
        int r = i >> 5, c = i & 31;
        int n = n0 + r;
        t[r][c] = (n < Nn) ? vbuf[((size_t)b * Nn + n) * DHn + c0 + c] : f2b(0.f);
    }
    __syncthreads();
    for (int i = tid; i < 1024; i += 256) {
        int r = i >> 5, c = i & 31;
        int n = n0 + c;   // n < 800 always (25*32 grid)
        vt[((size_t)b * DHn + c0 + r) * AST + n] = t[c][r];
    }
}

// ------------------------- colsum_v[b][c] = sum_n v[b][n][c]  (for b2 term)
__global__ __launch_bounds__(256) void k_vcolsum(
    const bf16* __restrict__ vbuf, float* __restrict__ colsum)
{
    __shared__ float red[4][64];
    const int b = blockIdx.y, c0 = blockIdx.x * 64;
    const int t = threadIdx.x, cl = t & 63, part = t >> 6;
    float s = 0.f;
    const int nst = part * 196;
    for (int n = nst; n < nst + 196; ++n)
        s += b2f(vbuf[((size_t)b * Nn + n) * DHn + c0 + cl]);
    red[part][cl] = s;
    __syncthreads();
    if (t < 64)
        colsum[(size_t)b * DHn + c0 + t] = red[0][t] + red[1][t] + red[2][t] + red[3][t];
}

// -------------------- frag-linear staging: 64 rows x 32 k of a K-contig matrix
__device__ __forceinline__ void stage64x32(const bf16* __restrict__ src,
    int row0, int row_lim, int k0, int k_lim, int ld, short* lds, int tid)
{
    int rsub = ((tid >> 6) << 4) | (tid & 15);
    int q    = (tid >> 4) & 3;
    int row = row0 + rsub; row = row < row_lim ? row : row_lim - 1;
    gload16((const short*)src + (size_t)row * ld + k0 + q * 8,
            lds + (size_t)(((rsub >> 4) * 4 + q) * 16 + (rsub & 15)) * 8);
}

// ------------------- generic MFMA core: tile (MI*32) x 128, BK=32, gload_lds
template<int MI>
__device__ __forceinline__ void gemm_core(
    const bf16* __restrict__ A, int lda, int rowsA, int arow0,
    const bf16* __restrict__ B, int ldb, int rowsB, int brow0,
    int K, short* ldsA, short* ldsB, f32x4 (&acc)[MI][4])
{
    const int tid  = threadIdx.x;
    const int lane = tid & 63;
    const int wm   = tid >> 7, wn = (tid >> 6) & 1;
    const short8v* A8 = (const short8v*)ldsA;
    const short8v* B8 = (const short8v*)ldsB;

    for (int k0 = 0; k0 < K; k0 += 32) {
        __syncthreads();
        #pragma unroll
        for (int c = 0; c < MI / 2; ++c)
            stage64x32(A, arow0 + c * 64, rowsA, k0, K, lda, ldsA + c * 2048, tid);
        #pragma unroll
        for (int c = 0; c < 2; ++c)
            stage64x32(B, brow0 + c * 64, rowsB, k0, K, ldb, ldsB + c * 2048, tid);
        __syncthreads();
        short8v a[MI], bb[4];
        #pragma unroll
        for (int i = 0; i < MI; ++i) a[i] = A8[(wm * MI + i) * 64 + lane];
        #pragma unroll
        for (int j = 0; j < 4; ++j) bb[j] = B8[(wn * 4 + j) * 64 + lane];
        #pragma unroll
        for (int i = 0; i < MI; ++i)
            #pragma unroll
            for (int j = 0; j < 4; ++j)
                acc[i][j] = __builtin_amdgcn_mfma_f32_16x16x32_bf16(a[i], bb[j], acc[i][j], 0, 0, 0);
    }
}

#define EPI_COORDS(MI)                                      \
    const int tid  = threadIdx.x;                           \
    const int lane = tid & 63;                              \
    const int wm   = tid >> 7, wn = (tid >> 6) & 1;         \
    const int rq   = lane >> 4, cl = lane & 15; (void)rq;

// --------------------------------------------- q/k/v projection + BN (MFMA)
__global__ __launch_bounds__(256) void k_proj_m(
    const bf16* __restrict__ xt, const bf16* __restrict__ Wqkv,
    const float* __restrict__ al, const float* __restrict__ be,
    bf16* __restrict__ qbuf, bf16* __restrict__ kbuf, bf16* __restrict__ vbuf)
{
    __shared__ short ldsA[4096], ldsB[4096];
    const int n0 = blockIdx.x * 128, co0 = blockIdx.y * 128;
    const int b = blockIdx.z;
    f32x4 acc[4][4] = {};
    gemm_core<4>(xt + (size_t)b * Nn * CIN, CIN, Nn, n0,
                 Wqkv, CIN, 1536, co0, CIN, ldsA, ldsB, acc);
    EPI_COORDS(4)
    #pragma unroll
    for (int i = 0; i < 4; ++i)
        #pragma unroll
        for (int j = 0; j < 4; ++j) {
            int co = co0 + (wn * 4 + j) * 16 + cl;
            float a_ = al[co], bb_ = be[co];
            int nb = n0 + (wm * 4 + i) * 16 + rq * 4;
            #pragma unroll
            for (int r = 0; r < 4; ++r) {
                int n = nb + r;
                if (n >= Nn) continue;
                float y = a_ * acc[i][j][r] + bb_;
                if (co < 256)      qbuf[((size_t)b * Nn + n) * 256 + co]       = f2b(y);
                else if (co < 512) kbuf[((size_t)b * Nn + n) * 256 + (co-256)] = f2b(y);
                else               vbuf[((size_t)b * Nn + n) * DHn + (co-512)] = f2b(y);
            }
        }
}

// ----------------------- raw per-head logits: qk[h][n][m], K=32 (no mix/bias)
__global__ __launch_bounds__(256) void k_logits_raw(
    const bf16* __restrict__ qbuf, const bf16* __restrict__ kbuf,
    bf16* __restrict__ attn, int bi0)
{
    __shared__ short ldsA[4096], ldsB[4096];
    const int n0 = blockIdx.x * 128, m0 = blockIdx.y * 128;
    const int z = blockIdx.z, h = z & 7, bloc = z >> 3, b = bi0 + bloc;
    f32x4 acc[4][4] = {};
    gemm_core<4>(qbuf + (size_t)b * Nn * 256 + h * 32, 256, Nn, n0,
                 kbuf + (size_t)b * Nn * 256 + h * 32, 256, Nn, m0,
                 32, ldsA, ldsB, acc);
    bf16* arow = attn + (size_t)(bloc * 8 + h) * Nn * AST;
    EPI_COORDS(4)
    #pragma unroll
    for (int i = 0; i < 4; ++i)
        #pragma unroll
        for (int j = 0; j < 4; ++j) {
            int m = m0 + (wn * 4 + j) * 16 + cl;
            if (m >= Nn) continue;
            int nb = n0 + (wm * 4 + i) * 16 + rq * 4;
            #pragma unroll
            for (int r = 0; r < 4; ++r) {
                int n = nb + r;
                if (n < Nn) arow[(size_t)n * AST + m] = f2b(acc[i][j][r]);
            }
        }
}

// --- fused: th1 mix (+abfull) + softmax (no-max) + th2 mix (NO b2) -> bf8 P2
__global__ __launch_bounds__(256) void k_softmax_mix(
    const bf16* __restrict__ attn_all, unsigned char* __restrict__ p2_all,
    const bf16* __restrict__ abfull,
    const bf16* __restrict__ W1, const bf16* __restrict__ W2)
{
    const int n = blockIdx.x, bloc = blockIdx.y;
    const int tid = threadIdx.x;
    const bf16* base = attn_all + (size_t)bloc * 8 * Nn * AST;
    unsigned char* p2b = p2_all + (size_t)bloc * 8 * Nn * AST;
    __shared__ float w1s[64], w2s[64], lis[8], wred[4][8];
    if (tid < 64) { w1s[tid] = b2f(W1[tid]) * 0.17677669529663687f; w2s[tid] = b2f(W2[tid]); }
    __syncthreads();

    const bool live = tid < 196;
    const int m0 = (live ? tid : 195) * 4;

    f32x2 raw2[8][2];
    #pragma unroll
    for (int h = 0; h < 8; ++h) {
        short4v v = *(const short4v*)(base + ((size_t)h * Nn + n) * AST + m0);
        raw2[h][0] = f32x2{su2f(v[0]), su2f(v[1])};
        raw2[h][1] = f32x2{su2f(v[2]), su2f(v[3])};
    }

    float out[8][4];
    #pragma unroll
    for (int g = 0; g < 8; ++g) {
        short4v bv = *(const short4v*)(abfull + ((size_t)g * Nn + n) * AST + m0);
        f32x2 a0 = {su2f(bv[0]), su2f(bv[1])};
        f32x2 a1 = {su2f(bv[2]), su2f(bv[3])};
        #pragma unroll
        for (int h = 0; h < 8; ++h) {
            float w = w1s[g * 8 + h];
            f32x2 wv = {w, w};
            a0 += raw2[h][0] * wv;
            a1 += raw2[h][1] * wv;
        }
        out[g][0] = __expf(fminf(a0[0], 60.f));
        out[g][1] = __expf(fminf(a0[1], 60.f));
        out[g][2] = __expf(fminf(a1[0], 60.f));
        out[g][3] = __expf(fminf(a1[1], 60.f));
        float s = live ? (out[g][0] + out[g][1]) + (out[g][2] + out[g][3]) : 0.f;
        #pragma unroll
        for (int sh = 32; sh > 0; sh >>= 1) s += __shfl_xor(s, sh, 64);
        if ((tid & 63) == 0) wred[tid >> 6][g] = s;
    }
    __syncthreads();
    if (tid < 8)
        lis[tid] = 1.f / (wred[0][tid] + wred[1][tid] + wred[2][tid] + wred[3][tid]);
    __syncthreads();

    f32x2 p2[8][2];
    #pragma unroll
    for (int h = 0; h < 8; ++h) {
        float lh = lis[h];
        p2[h][0] = f32x2{out[h][0] * lh, out[h][1] * lh};
        p2[h][1] = f32x2{out[h][2] * lh, out[h][3] * lh};
    }
    if (live) {
        #pragma unroll
        for (int g = 0; g < 8; ++g) {
            f32x2 acc0 = {0.f, 0.f};
            f32x2 acc1 = {0.f, 0.f};
            #pragma unroll
            for (int h = 0; h < 8; ++h) {
                float w = w2s[g * 8 + h];
                f32x2 wv = {w, w};
                acc0 += p2[h][0] * wv;
                acc1 += p2[h][1] * wv;
            }
            unsigned u = pack4_bf8(acc0[0], acc0[1], acc1[0], acc1[1]);
            *(unsigned*)(p2b + ((size_t)g * Nn + n) * AST + m0) = u;
        }
    }
}

// ------- PV: obuf[b][n][c] = P2mix(bf8) . v  + b2[g]*colsum_v  (MFMA bf16)
__global__ __launch_bounds__(256) void k_pv_m(
    const unsigned char* __restrict__ p2, const bf16* __restrict__ vt,
    const bf16* __restrict__ b2v, const float* __restrict__ colsum,
    bf16* __restrict__ obuf, int bi0)
{
    __shared__ short ldsA[2048], ldsB[4096];
    const int tid = threadIdx.x;
    const int n0 = blockIdx.x * 64;
    const int z = blockIdx.z, g = z & 7, bloc = z >> 3, b = bi0 + bloc;
    const unsigned char* Ap = p2 + (size_t)(bloc * 8 + g) * Nn * AST;
    const bf16* Bv = vt + ((size_t)b * DHn + g * 128) * AST;
    const int lane = tid & 63;
    const int wm = tid >> 7, wn = (tid >> 6) & 1;
    const int rsub = ((tid >> 6) << 4) | (tid & 15);
    const int q = (tid >> 4) & 3;
    const short8v* A8 = (const short8v*)ldsA;
    const short8v* B8 = (const short8v*)ldsB;
    f32x4 acc[2][4] = {};

    for (int k0 = 0; k0 < AST; k0 += 32) {
        __syncthreads();
        {   // A stage: load 8 bf8 bytes, HW-decode -> bf16 frag slot
            int row = n0 + rsub; row = row < Nn ? row : Nn - 1;
            const unsigned char* src = Ap + (size_t)row * AST + k0 + q * 8;
            unsigned lo = *(const unsigned*)src;
            unsigned hi = *(const unsigned*)(src + 4);
            float d0[4], d1[4];
            unpack4_bf8(lo, d0);
            unpack4_bf8(hi, d1);
            short8v o;
            #pragma unroll
            for (int j = 0; j < 4; ++j) { o[j] = f2s(d0[j]); o[4 + j] = f2s(d1[j]); }
            ((short8v*)ldsA)[((rsub >> 4) * 4 + q) * 16 + (rsub & 15)] = o;
        }
        stage64x32(Bv, 0,  128, k0, AST, AST, ldsB, tid);
        stage64x32(Bv, 64, 128, k0, AST, AST, ldsB + 2048, tid);
        __syncthreads();
        short8v a[2], bb[4];
        #pragma unroll
        for (int i = 0; i < 2; ++i) a[i] = A8[(wm * 2 + i) * 64 + lane];
        #pragma unroll
        for (int j = 0; j < 4; ++j) bb[j] = B8[(wn * 4 + j) * 64 + lane];
        #pragma unroll
        for (int i = 0; i < 2; ++i)
            #pragma unroll
            for (int j = 0; j < 4; ++j)
                acc[i][j] = __builtin_amdgcn_mfma_f32_16x16x32_bf16(a[i], bb[j], acc[i][j], 0, 0, 0);
    }

    bf16* ob = obuf + (size_t)b * Nn * DHn + g * 128;
    const float b2g = b2f(b2v[g]);
    const int rq = lane >> 4, cl = lane & 15;
    #pragma unroll
    for (int i = 0; i < 2; ++i)
        #pragma unroll
        for (int j = 0; j < 4; ++j) {
            int d = (wn * 4 + j) * 16 + cl;
            float cs = b2g * colsum[(size_t)b * DHn + g * 128 + d];
            int nb = n0 + (wm * 2 + i) * 16 + rq * 4;
            #pragma unroll
            for (int r = 0; r < 4; ++r) {
                int n = nb + r;
                if (n < Nn) ob[(size_t)n * DHn + d] = f2b(acc[i][j][r] + cs);
            }
        }
}

// ---- depthwise conv+BN, ADDS into obuf (o += vl), fully vectorized weights
__global__ __launch_bounds__(256) void k_dwconv_add(
    const bf16* __restrict__ vbuf, const bf16* __restrict__ Wvlt,
    const bf16* __restrict__ bvl, const bf16* __restrict__ vls, const bf16* __restrict__ vlb,
    bf16* __restrict__ obuf)
{
    const int t = threadIdx.x;
    const int n = blockIdx.y * 2 + (t >> 7);
    const int bi = blockIdx.z;
    const int c0 = (t & 127) * 8;
    const int h = n / RESn, w = n % RESn;
    float acc[8] = {};
    #pragma unroll
    for (int dh = -1; dh <= 1; ++dh)
        #pragma unroll
        for (int dw = -1; dw <= 1; ++dw) {
            int hh = h + dh, ww = w + dw;
            if (hh < 0 || hh >= RESn || ww < 0 || ww >= RESn) continue;
            int widx = (dh + 1) * 3 + (dw + 1);
            short8v wv = *(const short8v*)&Wvlt[widx * 1024 + c0];
            short8v v  = *(const short8v*)&vbuf[((size_t)bi * Nn + hh * RESn + ww) * DHn + c0];
            #pragma unroll
            for (int u = 0; u < 8; ++u)
                acc[u] += su2f(wv[u]) * su2f(v[u]);
        }
    short8v bv = *(const short8v*)&bvl[c0];
    short8v sv = *(const short8v*)&vls[c0];
    short8v hv = *(const short8v*)&vlb[c0];
    size_t off = ((size_t)bi * Nn + n) * DHn + c0;
    short8v ov = *(short8v*)&obuf[off];
    short8v res;
    #pragma unroll
    for (int u = 0; u < 8; ++u) {
        float vl = su2f(sv[u]) * (acc[u] + su2f(bv[u])) + su2f(hv[u]);
        res[u] = f2s(su2f(ov[u]) + vl);
    }
    *(short8v*)&obuf[off] = res;
}

// --------------------------------------------- output projection + BN (MFMA)
__global__ __launch_bounds__(256) void k_outproj_m(
    const bf16* __restrict__ Wp, const bf16* __restrict__ obuf,
    const bf16* __restrict__ bp, const bf16* __restrict__ ps, const bf16* __restrict__ pb,
    void* __restrict__ outv, const int* __restrict__ flag)
{
    __shared__ short ldsA[2048], ldsB[4096];
    const int n0 = blockIdx.x * 128, oc0 = blockIdx.y * 64;
    const int b = blockIdx.z;
    f32x4 acc[2][4] = {};
    gemm_core<2>(Wp, DHn, 384, oc0,
                 obuf + (size_t)b * Nn * DHn, DHn, Nn, n0,
                 DHn, ldsA, ldsB, acc);
    const int isb = *flag;
    EPI_COORDS(2)
    #pragma unroll
    for (int i = 0; i < 2; ++i)
        #pragma unroll
        for (int j = 0; j < 4; ++j) {
            int n = n0 + (wn * 4 + j) * 16 + cl;
            if (n >= Nn) continue;
            int ocb = oc0 + (wm * 2 + i) * 16 + rq * 4;
            #pragma unroll
            for (int r = 0; r < 4; ++r) {
                int oc = ocb + r;
                float a_ = b2f(ps[oc]);
                float be_ = b2f(bp[oc]) * a_ + b2f(pb[oc]);
                float y = a_ * acc[i][j][r] + be_;
                size_t idx = ((size_t)b * CIN + oc) * Nn + n;
                if (isb) ((bf16*)outv)[idx] = f2b(y);
                else     ((float*)outv)[idx] = y;
            }
        }
}

extern "C" void kernel_launch(void* const* d_in, const int* in_sizes, int n_in,
                              void* d_out, int out_size, void* d_ws, size_t ws_size,
                              hipStream_t stream)
{
    char* ws = (char*)d_ws;
    auto align256 = [](size_t v) { return (v + 255) & ~(size_t)255; };

    size_t off = 0;
    size_t off_flag = off;            off = align256(off + 4);
    size_t p_off[26];
    for (int i = 0; i < 26; ++i) { p_off[i] = off; off = align256(off + (size_t)in_sizes[i] * 2); }
    size_t off_mb   = off; off = align256(off + (size_t)8 * Nn * 4);
    size_t off_ab   = off; off = align256(off + (size_t)8 * Nn * AST * 2);
    size_t off_q    = off; off = align256(off + (size_t)Bn * Nn * 256 * 2);
    size_t off_k    = off; off = align256(off + (size_t)Bn * Nn * 256 * 2);
    size_t off_v    = off; off = align256(off + (size_t)Bn * Nn * DHn * 2);
    size_t off_vt   = off; off = align256(off + (size_t)Bn * DHn * AST * 2);
    size_t off_o    = off; off = align256(off + (size_t)Bn * Nn * DHn * 2);
    size_t off_xt   = off; off = align256(off + (size_t)Bn * Nn * CIN * 2);
    size_t off_wqkv = off; off = align256(off + (size_t)1536 * CIN * 2);
    size_t off_al   = off; off = align256(off + (size_t)1536 * 4);
    size_t off_be   = off; off = align256(off + (size_t)1536 * 4);
    size_t off_wvlt = off; off = align256(off + (size_t)9 * 1024 * 2);
    size_t off_cs   = off; off = align256(off + (size_t)Bn * DHn * 4);
    size_t base = off;

    const size_t attn_per_b = (size_t)8 * Nn * AST * 2;  // S bf16
    const size_t p2_per_b   = (size_t)8 * Nn * AST;      // P2 bf8
    int GB = 0;
    const int cand[4] = {8, 4, 2, 1};
    for (int ci = 0; ci < 4; ++ci) {
        if (base + (size_t)cand[ci] * (attn_per_b + p2_per_b) + 512 <= ws_size) { GB = cand[ci]; break; }
    }
    if (!GB) return; // ws too small -> zeros out (diagnostic absmax ~17.4)

    size_t off_attn = base;
    size_t off_p2   = align256(off_attn + (size_t)GB * attn_per_b);

    int*  flag = (int*)(ws + off_flag);
    bf16* Pb[26];
    for (int i = 0; i < 26; ++i) Pb[i] = (bf16*)(ws + p_off[i]);
    float* mb    = (float*)(ws + off_mb);
    bf16* abfull = (bf16*)(ws + off_ab);
    bf16* qbuf  = (bf16*)(ws + off_q);
    bf16* kbuf  = (bf16*)(ws + off_k);
    bf16* vbuf  = (bf16*)(ws + off_v);
    bf16* vt    = (bf16*)(ws + off_vt);
    bf16* obuf  = (bf16*)(ws + off_o);
    bf16* xt    = (bf16*)(ws + off_xt);
    bf16* wqkv  = (bf16*)(ws + off_wqkv);
    float* alf  = (float*)(ws + off_al);
    float* bef  = (float*)(ws + off_be);
    bf16* wvlt  = (bf16*)(ws + off_wvlt);
    float* csum = (float*)(ws + off_cs);
    bf16* attn  = (bf16*)(ws + off_attn);
    unsigned char* p2b = (unsigned char*)(ws + off_p2);
    const int* idxs = (const int*)d_in[26];

    k_detect<<<1, 64, 0, stream>>>((const unsigned*)d_in[0], flag);

    PtrArgs pa;
    for (int i = 0; i < 26; ++i) pa.p[i] = d_in[i];
    k_prep<<<dim3(288, 4), 256, 0, stream>>>(pa, wqkv, alf, bef, mb, wvlt, flag);

    const int cidx[10] = {14, 15, 16, 17, 19, 20, 21, 22, 23, 24};
    ConvArgs ca;
    for (int i = 0; i < 10; ++i) {
        ca.src[i] = d_in[cidx[i]];
        ca.dstoff[i] = p_off[cidx[i]];
        ca.n[i] = in_sizes[cidx[i]];
    }
    k_convb_all<<<dim3(64, 10), 256, 0, stream>>>(ca, ws, flag);

    bf16 *bvl = Pb[14], *vls = Pb[15], *vlb = Pb[16],
         *W1 = Pb[17], *W2 = Pb[19], *b2v = Pb[20],
         *Wp = Pb[21], *bp = Pb[22], *ps = Pb[23], *pb = Pb[24];

    k_xt<<<dim3(25, 12, 8), 256, 0, stream>>>(d_in[0], xt, flag);
    k_abfull<<<dim3(392), 256, 0, stream>>>(mb, idxs, abfull);

    k_proj_m<<<dim3(7, 12, 8), 256, 0, stream>>>(xt, wqkv, alf, bef, qbuf, kbuf, vbuf);
    k_vt<<<dim3(25, 32, 8), 256, 0, stream>>>(vbuf, vt);
    k_vcolsum<<<dim3(16, 8), 256, 0, stream>>>(vbuf, csum);

    for (int bi0 = 0; bi0 < Bn; bi0 += GB) {
        k_logits_raw<<<dim3(7, 7, GB * 8), 256, 0, stream>>>(qbuf, kbuf, attn, bi0);
        k_softmax_mix<<<dim3(Nn, GB), 256, 0, stream>>>(attn, p2b, abfull, W1, W2);
        k_pv_m<<<dim3(13, 1, GB * 8), 256, 0, stream>>>(p2b, vt, b2v, csum, obuf, bi0);
    }

    k_dwconv_add<<<dim3(1, Nn / 2, 8), 256, 0, stream>>>(vbuf, wvlt, bvl, vls, vlb, obuf);
    k_outproj_m<<<dim3(7, 6, 8), 256, 0, stream>>>(Wp, obuf, bp, ps, pb, d_out, flag);
}

// Round 15
// 231.647 us; speedup vs baseline: 1.0483x; 1.0179x over previous
//
#include <hip/hip_runtime.h>
#include <hip/hip_bf16.h>
#include <hip/hip_fp16.h>

typedef __hip_bfloat16 bf16;
typedef __attribute__((ext_vector_type(8))) short short8v;
typedef __attribute__((ext_vector_type(4))) short short4v;
typedef __attribute__((ext_vector_type(4))) float f32x4;
typedef __attribute__((ext_vector_type(2))) float f32x2;

__device__ __forceinline__ float b2f(bf16 v){ return __bfloat162float(v); }
__device__ __forceinline__ bf16  f2b(float v){ return __float2bfloat16(v); }
__device__ __forceinline__ float su2f(short s){
    unsigned short us = (unsigned short)s;
    return __bfloat162float(*reinterpret_cast<bf16*>(&us));
}
__device__ __forceinline__ short f2s(float v){
    bf16 b = __float2bfloat16(v);
    return *reinterpret_cast<short*>(&b);
}
__device__ __forceinline__ float ldf(const void* t, size_t i, int isb){
    return isb ? b2f(((const bf16*)t)[i]) : ((const float*)t)[i];
}

// ---- bf8 (e5m2) codec: HW cvt_pk if available, else f16-path software RNE ----
__device__ __forceinline__ unsigned f2bf8_sw(float f){
    unsigned short h = __half_as_ushort(__float2half(f));
    unsigned lsb = (h >> 8) & 1u, rb = (h >> 7) & 1u, st = (h & 0x7Fu) ? 1u : 0u;
    return ((unsigned)(h >> 8) + (rb & (st | lsb))) & 0xFFu;
}
__device__ __forceinline__ float bf82f_sw(unsigned b){
    return __half2float(__ushort_as_half((unsigned short)(b << 8)));
}
__device__ __forceinline__ unsigned pack4_bf8(float a0, float a1, float a2, float a3){
#if __has_builtin(__builtin_amdgcn_cvt_pk_bf8_f32)
    int u = __builtin_amdgcn_cvt_pk_bf8_f32(a0, a1, 0, false);
    u = __builtin_amdgcn_cvt_pk_bf8_f32(a2, a3, u, true);
    return (unsigned)u;
#else
    return f2bf8_sw(a0) | (f2bf8_sw(a1) << 8) | (f2bf8_sw(a2) << 16) | (f2bf8_sw(a3) << 24);
#endif
}
__device__ __forceinline__ unsigned f2bf8_1(float f){
#if __has_builtin(__builtin_amdgcn_cvt_pk_bf8_f32)
    return (unsigned)__builtin_amdgcn_cvt_pk_bf8_f32(f, f, 0, false) & 0xFFu;
#else
    return f2bf8_sw(f);
#endif
}
__device__ __forceinline__ void unpack4_bf8(unsigned u, float* o){
#if __has_builtin(__builtin_amdgcn_cvt_pk_f32_bf8)
    f32x2 lo = __builtin_amdgcn_cvt_pk_f32_bf8((int)u, false);
    f32x2 hi = __builtin_amdgcn_cvt_pk_f32_bf8((int)u, true);
    o[0] = lo[0]; o[1] = lo[1]; o[2] = hi[0]; o[3] = hi[1];
#else
    o[0] = bf82f_sw(u & 0xFFu);         o[1] = bf82f_sw((u >> 8) & 0xFFu);
    o[2] = bf82f_sw((u >> 16) & 0xFFu); o[3] = bf82f_sw((u >> 24) & 0xFFu);
#endif
}

constexpr int Bn = 8, CIN = 384, RESn = 28, Nn = 784, DHn = 1024;
constexpr int AST = 800;   // padded attn/vt K-stride (25*32)

// ---------------------------------------------------- async global->LDS 16B
__device__ __forceinline__ void gload16(const void* g, void* l)
{
    __builtin_amdgcn_global_load_lds(
        (const __attribute__((address_space(1))) void*)g,
        (__attribute__((address_space(3))) void*)l, 16, 0, 0);
}

// -------------------------------------------------- dtype detector (1 thread)
__global__ void k_detect(const unsigned* __restrict__ xw, int* __restrict__ flag)
{
    if (blockIdx.x == 0 && threadIdx.x == 0) {
        int cnt = 0;
        for (int i = 0; i < 256; ++i) {
            unsigned lo = xw[i] & 0xFFFFu;
            int e = (int)((lo >> 7) & 0xFF);
            if (e >= 112 && e <= 132) ++cnt;
        }
        *flag = (cnt >= 128) ? 1 : 0;
    }
}

// -- fused prep: wpack | affine | mixbias | dw-weight transpose (reads d_in raw)
struct PtrArgs { const void* p[26]; };
__global__ __launch_bounds__(256) void k_prep(PtrArgs a, bf16* __restrict__ Wqkv,
                                              float* __restrict__ al, float* __restrict__ be,
                                              float* __restrict__ mb, bf16* __restrict__ Wvlt,
                                              const int* __restrict__ flag)
{
    const int isb = *flag;
    const int tid = threadIdx.x;
    const int role = blockIdx.y;
    if (role == 0) {
        int stride = gridDim.x * 256;
        for (int e = blockIdx.x * 256 + tid; e < 1536 * 384; e += stride) {
            int co = e / 384, k = e % 384;
            const void* src; int lc;
            if (co < 256)      { src = a.p[1]; lc = co; }
            else if (co < 512) { src = a.p[5]; lc = co - 256; }
            else               { src = a.p[9]; lc = co - 512; }
            Wqkv[e] = f2b(ldf(src, (size_t)lc * 384 + k, isb));
        }
    } else if (role == 1) {
        int co = blockIdx.x * 256 + tid;
        if (co < 1536) {
            const void *b_, *s_, *h_; int lc;
            if (co < 256)      { b_ = a.p[2];  s_ = a.p[3];  h_ = a.p[4];  lc = co; }
            else if (co < 512) { b_ = a.p[6];  s_ = a.p[7];  h_ = a.p[8];  lc = co - 256; }
            else               { b_ = a.p[10]; s_ = a.p[11]; h_ = a.p[12]; lc = co - 512; }
            float aa = ldf(s_, lc, isb);
            al[co] = aa;
            be[co] = ldf(b_, lc, isb) * aa + ldf(h_, lc, isb);
        }
    } else if (role == 2) {
        int i = blockIdx.x * 256 + tid;
        if (i < 8 * Nn) {
            int g = i / Nn, p = i % Nn;
            float acc = ldf(a.p[18], g, isb);
            #pragma unroll
            for (int h = 0; h < 8; ++h)
                acc += ldf(a.p[17], g * 8 + h, isb) * ldf(a.p[25], (size_t)h * Nn + p, isb);
            mb[i] = acc;
        }
    } else {
        int e = blockIdx.x * 256 + tid;   // Wvl [1024][9] -> Wvlt [9][1024]
        if (e < 1024 * 9) {
            int c = e / 9, tap = e % 9;
            Wvlt[tap * 1024 + c] = f2b(ldf(a.p[13], e, isb));
        }
    }
}

// ------------------------------------- convert needed tensors -> bf16
struct ConvArgs { const void* src[10]; unsigned long long dstoff[10]; int n[10]; };
__global__ void k_convb_all(ConvArgs a, char* __restrict__ ws, const int* __restrict__ flag)
{
    int i = blockIdx.y;
    int n = a.n[i];
    const void* s = a.src[i];
    bf16* d = (bf16*)(ws + a.dstoff[i]);
    int isb = *flag;
    int stride = gridDim.x * blockDim.x;
    for (int t = blockIdx.x * blockDim.x + threadIdx.x; t < n; t += stride)
        d[t] = isb ? ((const bf16*)s)[t] : f2b(((const float*)s)[t]);
}

// ------------------- expand mb through idx: abfull[g][n][m] (b-independent)
__global__ __launch_bounds__(256) void k_abfull(
    const float* __restrict__ mb, const int* __restrict__ idxs,
    bf16* __restrict__ abfull)
{
    __shared__ float mbs[8][Nn];
    const int tid = threadIdx.x;
    for (int i = tid; i < 8 * Nn; i += 256) ((float*)mbs)[i] = mb[i];
    __syncthreads();
    const int nstart = blockIdx.x * 2;
    for (int n = nstart; n < nstart + 2; ++n) {
        for (int m = tid; m < Nn; m += 256) {
            int id = idxs[(size_t)n * Nn + m];
            #pragma unroll
            for (int g = 0; g < 8; ++g)
                abfull[((size_t)g * Nn + n) * AST + m] = f2b(mbs[g][id]);
        }
    }
}

// ------------- x transpose + inline convert: [b][384][784] -> [b][784][384]
__global__ __launch_bounds__(256) void k_xt(const void* __restrict__ xr, bf16* __restrict__ xt,
                                            const int* __restrict__ flag)
{
    const int isb = *flag;
    __shared__ bf16 t[32][33];
    int b = blockIdx.z, n0 = blockIdx.x * 32, c0 = blockIdx.y * 32;
    int tid = threadIdx.x;
    for (int i = tid; i < 1024; i += 256) {
        int r = i >> 5, c = i & 31;
        int n = n0 + c;
        t[r][c] = (n < Nn) ? f2b(ldf(xr, ((size_t)b * CIN + c0 + r) * Nn + n, isb)) : f2b(0.f);
    }
    __syncthreads();
    for (int i = tid; i < 1024; i += 256) {
        int r = i >> 5, c = i & 31;
        int n = n0 + r;
        if (n < Nn) xt[((size_t)b * Nn + n) * CIN + c0 + c] = t[c][r];
    }
}

// --------------------- v transpose: [n][c] -> [c][n] (stride AST, zero-padded)
__global__ __launch_bounds__(256) void k_vt(const bf16* __restrict__ vbuf, bf16* __restrict__ vt)
{
    __shared__ bf16 t[32][33];
    int b = blockIdx.z, n0 = blockIdx.x * 32, c0 = blockIdx.y * 32;
    int tid = threadIdx.x;
    for (int i = tid; i < 1024; i += 256) {
        int r = i >> 5, c = i & 31;
        int n = n0 + r;
        t[r][c] = (n < Nn) ? vbuf[((size_t)b * Nn + n) * DHn + c0 + c] : f2b(0.f);
    }
    __syncthreads();
    for (int i = tid; i < 1024; i += 256) {
        int r = i >> 5, c = i & 31;
        int n = n0 + c;   // n < 800 always (25*32 grid)
        vt[((size_t)b * DHn + c0 + r) * AST + n] = t[c][r];
    }
}

// ------------------------- colsum_v[b][c] = sum_n v[b][n][c]  (for b2 term)
__global__ __launch_bounds__(256) void k_vcolsum(
    const bf16* __restrict__ vbuf, float* __restrict__ colsum)
{
    __shared__ float red[4][64];
    const int b = blockIdx.y, c0 = blockIdx.x * 64;
    const int t = threadIdx.x, cl = t & 63, part = t >> 6;
    float s = 0.f;
    const int nst = part * 196;
    for (int n = nst; n < nst + 196; ++n)
        s += b2f(vbuf[((size_t)b * Nn + n) * DHn + c0 + cl]);
    red[part][cl] = s;
    __syncthreads();
    if (t < 64)
        colsum[(size_t)b * DHn + c0 + t] = red[0][t] + red[1][t] + red[2][t] + red[3][t];
}

// -------------------- frag-linear staging: 64 rows x 32 k of a K-contig matrix
__device__ __forceinline__ void stage64x32(const bf16* __restrict__ src,
    int row0, int row_lim, int k0, int k_lim, int ld, short* lds, int tid)
{
    int rsub = ((tid >> 6) << 4) | (tid & 15);
    int q    = (tid >> 4) & 3;
    int row = row0 + rsub; row = row < row_lim ? row : row_lim - 1;
    gload16((const short*)src + (size_t)row * ld + k0 + q * 8,
            lds + (size_t)(((rsub >> 4) * 4 + q) * 16 + (rsub & 15)) * 8);
}

// ------------------- generic MFMA core: tile (MI*32) x 128, BK=32, gload_lds
template<int MI>
__device__ __forceinline__ void gemm_core(
    const bf16* __restrict__ A, int lda, int rowsA, int arow0,
    const bf16* __restrict__ B, int ldb, int rowsB, int brow0,
    int K, short* ldsA, short* ldsB, f32x4 (&acc)[MI][4])
{
    const int tid  = threadIdx.x;
    const int lane = tid & 63;
    const int wm   = tid >> 7, wn = (tid >> 6) & 1;
    const short8v* A8 = (const short8v*)ldsA;
    const short8v* B8 = (const short8v*)ldsB;

    for (int k0 = 0; k0 < K; k0 += 32) {
        __syncthreads();
        #pragma unroll
        for (int c = 0; c < MI / 2; ++c)
            stage64x32(A, arow0 + c * 64, rowsA, k0, K, lda, ldsA + c * 2048, tid);
        #pragma unroll
        for (int c = 0; c < 2; ++c)
            stage64x32(B, brow0 + c * 64, rowsB, k0, K, ldb, ldsB + c * 2048, tid);
        __syncthreads();
        short8v a[MI], bb[4];
        #pragma unroll
        for (int i = 0; i < MI; ++i) a[i] = A8[(wm * MI + i) * 64 + lane];
        #pragma unroll
        for (int j = 0; j < 4; ++j) bb[j] = B8[(wn * 4 + j) * 64 + lane];
        #pragma unroll
        for (int i = 0; i < MI; ++i)
            #pragma unroll
            for (int j = 0; j < 4; ++j)
                acc[i][j] = __builtin_amdgcn_mfma_f32_16x16x32_bf16(a[i], bb[j], acc[i][j], 0, 0, 0);
    }
}

#define EPI_COORDS(MI)                                      \
    const int tid  = threadIdx.x;                           \
    const int lane = tid & 63;                              \
    const int wm   = tid >> 7, wn = (tid >> 6) & 1;         \
    const int rq   = lane >> 4, cl = lane & 15; (void)rq;

// --------------------------------------------- q/k/v projection + BN (MFMA)
__global__ __launch_bounds__(256) void k_proj_m(
    const bf16* __restrict__ xt, const bf16* __restrict__ Wqkv,
    const float* __restrict__ al, const float* __restrict__ be,
    bf16* __restrict__ qbuf, bf16* __restrict__ kbuf, bf16* __restrict__ vbuf)
{
    __shared__ short ldsA[4096], ldsB[4096];
    const int n0 = blockIdx.x * 128, co0 = blockIdx.y * 128;
    const int b = blockIdx.z;
    f32x4 acc[4][4] = {};
    gemm_core<4>(xt + (size_t)b * Nn * CIN, CIN, Nn, n0,
                 Wqkv, CIN, 1536, co0, CIN, ldsA, ldsB, acc);
    EPI_COORDS(4)
    #pragma unroll
    for (int i = 0; i < 4; ++i)
        #pragma unroll
        for (int j = 0; j < 4; ++j) {
            int co = co0 + (wn * 4 + j) * 16 + cl;
            float a_ = al[co], bb_ = be[co];
            int nb = n0 + (wm * 4 + i) * 16 + rq * 4;
            #pragma unroll
            for (int r = 0; r < 4; ++r) {
                int n = nb + r;
                if (n >= Nn) continue;
                float y = a_ * acc[i][j][r] + bb_;
                if (co < 256)      qbuf[((size_t)b * Nn + n) * 256 + co]       = f2b(y);
                else if (co < 512) kbuf[((size_t)b * Nn + n) * 256 + (co-256)] = f2b(y);
                else               vbuf[((size_t)b * Nn + n) * DHn + (co-512)] = f2b(y);
            }
        }
}

// ------------- raw per-head logits: qk[h][n][m] -> bf8, K=32 (no mix/bias)
__global__ __launch_bounds__(256) void k_logits_raw(
    const bf16* __restrict__ qbuf, const bf16* __restrict__ kbuf,
    unsigned char* __restrict__ attn, int bi0)
{
    __shared__ short ldsA[4096], ldsB[4096];
    const int n0 = blockIdx.x * 128, m0 = blockIdx.y * 128;
    const int z = blockIdx.z, h = z & 7, bloc = z >> 3, b = bi0 + bloc;
    f32x4 acc[4][4] = {};
    gemm_core<4>(qbuf + (size_t)b * Nn * 256 + h * 32, 256, Nn, n0,
                 kbuf + (size_t)b * Nn * 256 + h * 32, 256, Nn, m0,
                 32, ldsA, ldsB, acc);
    unsigned char* arow = attn + (size_t)(bloc * 8 + h) * Nn * AST;
    EPI_COORDS(4)
    #pragma unroll
    for (int i = 0; i < 4; ++i)
        #pragma unroll
        for (int j = 0; j < 4; ++j) {
            int m = m0 + (wn * 4 + j) * 16 + cl;
            if (m >= Nn) continue;
            int nb = n0 + (wm * 4 + i) * 16 + rq * 4;
            #pragma unroll
            for (int r = 0; r < 4; ++r) {
                int n = nb + r;
                if (n < Nn) arow[(size_t)n * AST + m] = (unsigned char)f2bf8_1(acc[i][j][r]);
            }
        }
}

// --- fused: th1 mix (+abfull) + softmax (no-max) + th2 mix (NO b2) -> bf8 P2
__global__ __launch_bounds__(256) void k_softmax_mix(
    const unsigned char* __restrict__ attn_all, unsigned char* __restrict__ p2_all,
    const bf16* __restrict__ abfull,
    const bf16* __restrict__ W1, const bf16* __restrict__ W2)
{
    const int n = blockIdx.x, bloc = blockIdx.y;
    const int tid = threadIdx.x;
    const unsigned char* base = attn_all + (size_t)bloc * 8 * Nn * AST;
    unsigned char* p2b = p2_all + (size_t)bloc * 8 * Nn * AST;
    __shared__ float w1s[64], w2s[64], lis[8], wred[4][8];
    if (tid < 64) { w1s[tid] = b2f(W1[tid]) * 0.17677669529663687f; w2s[tid] = b2f(W2[tid]); }
    __syncthreads();

    const bool live = tid < 196;
    const int m0 = (live ? tid : 195) * 4;

    float raw[8][4];
    #pragma unroll
    for (int h = 0; h < 8; ++h) {
        unsigned u = *(const unsigned*)(base + ((size_t)h * Nn + n) * AST + m0);
        unpack4_bf8(u, raw[h]);
    }

    float out[8][4];
    #pragma unroll
    for (int g = 0; g < 8; ++g) {
        short4v bv = *(const short4v*)(abfull + ((size_t)g * Nn + n) * AST + m0);
        f32x2 a0 = {su2f(bv[0]), su2f(bv[1])};
        f32x2 a1 = {su2f(bv[2]), su2f(bv[3])};
        #pragma unroll
        for (int h = 0; h < 8; ++h) {
            float w = w1s[g * 8 + h];
            a0[0] += w * raw[h][0];
            a0[1] += w * raw[h][1];
            a1[0] += w * raw[h][2];
            a1[1] += w * raw[h][3];
        }
        out[g][0] = __expf(fminf(a0[0], 60.f));
        out[g][1] = __expf(fminf(a0[1], 60.f));
        out[g][2] = __expf(fminf(a1[0], 60.f));
        out[g][3] = __expf(fminf(a1[1], 60.f));
        float s = live ? (out[g][0] + out[g][1]) + (out[g][2] + out[g][3]) : 0.f;
        #pragma unroll
        for (int sh = 32; sh > 0; sh >>= 1) s += __shfl_xor(s, sh, 64);
        if ((tid & 63) == 0) wred[tid >> 6][g] = s;
    }
    __syncthreads();
    if (tid < 8)
        lis[tid] = 1.f / (wred[0][tid] + wred[1][tid] + wred[2][tid] + wred[3][tid]);
    __syncthreads();

    f32x2 p2[8][2];
    #pragma unroll
    for (int h = 0; h < 8; ++h) {
        float lh = lis[h];
        p2[h][0] = f32x2{out[h][0] * lh, out[h][1] * lh};
        p2[h][1] = f32x2{out[h][2] * lh, out[h][3] * lh};
    }
    if (live) {
        #pragma unroll
        for (int g = 0; g < 8; ++g) {
            f32x2 acc0 = {0.f, 0.f};
            f32x2 acc1 = {0.f, 0.f};
            #pragma unroll
            for (int h = 0; h < 8; ++h) {
                float w = w2s[g * 8 + h];
                f32x2 wv = {w, w};
                acc0 += p2[h][0] * wv;
                acc1 += p2[h][1] * wv;
            }
            unsigned u = pack4_bf8(acc0[0], acc0[1], acc1[0], acc1[1]);
            *(unsigned*)(p2b + ((size_t)g * Nn + n) * AST + m0) = u;
        }
    }
}

// ------- PV: obuf[b][n][c] = P2mix(bf8) . v  + b2[g]*colsum_v  (MFMA bf16)
__global__ __launch_bounds__(256) void k_pv_m(
    const unsigned char* __restrict__ p2, const bf16* __restrict__ vt,
    const bf16* __restrict__ b2v, const float* __restrict__ colsum,
    bf16* __restrict__ obuf, int bi0)
{
    __shared__ short ldsA[2048], ldsB[4096];
    const int tid = threadIdx.x;
    const int n0 = blockIdx.x * 64;
    const int z = blockIdx.z, g = z & 7, bloc = z >> 3, b = bi0 + bloc;
    const unsigned char* Ap = p2 + (size_t)(bloc * 8 + g) * Nn * AST;
    const bf16* Bv = vt + ((size_t)b * DHn + g * 128) * AST;
    const int lane = tid & 63;
    const int wm = tid >> 7, wn = (tid >> 6) & 1;
    const int rsub = ((tid >> 6) << 4) | (tid & 15);
    const int q = (tid >> 4) & 3;
    const short8v* A8 = (const short8v*)ldsA;
    const short8v* B8 = (const short8v*)ldsB;
    f32x4 acc[2][4] = {};

    for (int k0 = 0; k0 < AST; k0 += 32) {
        __syncthreads();
        {   // A stage: load 8 bf8 bytes, HW-decode -> bf16 frag slot
            int row = n0 + rsub; row = row < Nn ? row : Nn - 1;
            const unsigned char* src = Ap + (size_t)row * AST + k0 + q * 8;
            unsigned lo = *(const unsigned*)src;
            unsigned hi = *(const unsigned*)(src + 4);
            float d0[4], d1[4];
            unpack4_bf8(lo, d0);
            unpack4_bf8(hi, d1);
            short8v o;
            #pragma unroll
            for (int j = 0; j < 4; ++j) { o[j] = f2s(d0[j]); o[4 + j] = f2s(d1[j]); }
            ((short8v*)ldsA)[((rsub >> 4) * 4 + q) * 16 + (rsub & 15)] = o;
        }
        stage64x32(Bv, 0,  128, k0, AST, AST, ldsB, tid);
        stage64x32(Bv, 64, 128, k0, AST, AST, ldsB + 2048, tid);
        __syncthreads();
        short8v a[2], bb[4];
        #pragma unroll
        for (int i = 0; i < 2; ++i) a[i] = A8[(wm * 2 + i) * 64 + lane];
        #pragma unroll
        for (int j = 0; j < 4; ++j) bb[j] = B8[(wn * 4 + j) * 64 + lane];
        #pragma unroll
        for (int i = 0; i < 2; ++i)
            #pragma unroll
            for (int j = 0; j < 4; ++j)
                acc[i][j] = __builtin_amdgcn_mfma_f32_16x16x32_bf16(a[i], bb[j], acc[i][j], 0, 0, 0);
    }

    bf16* ob = obuf + (size_t)b * Nn * DHn + g * 128;
    const float b2g = b2f(b2v[g]);
    const int rq = lane >> 4, cl = lane & 15;
    #pragma unroll
    for (int i = 0; i < 2; ++i)
        #pragma unroll
        for (int j = 0; j < 4; ++j) {
            int d = (wn * 4 + j) * 16 + cl;
            float cs = b2g * colsum[(size_t)b * DHn + g * 128 + d];
            int nb = n0 + (wm * 2 + i) * 16 + rq * 4;
            #pragma unroll
            for (int r = 0; r < 4; ++r) {
                int n = nb + r;
                if (n < Nn) ob[(size_t)n * DHn + d] = f2b(acc[i][j][r] + cs);
            }
        }
}

// ---- depthwise conv+BN, ADDS into obuf (o += vl), fully vectorized weights
__global__ __launch_bounds__(256) void k_dwconv_add(
    const bf16* __restrict__ vbuf, const bf16* __restrict__ Wvlt,
    const bf16* __restrict__ bvl, const bf16* __restrict__ vls, const bf16* __restrict__ vlb,
    bf16* __restrict__ obuf)
{
    const int t = threadIdx.x;
    const int n = blockIdx.y * 2 + (t >> 7);
    const int bi = blockIdx.z;
    const int c0 = (t & 127) * 8;
    const int h = n / RESn, w = n % RESn;
    float acc[8] = {};
    #pragma unroll
    for (int dh = -1; dh <= 1; ++dh)
        #pragma unroll
        for (int dw = -1; dw <= 1; ++dw) {
            int hh = h + dh, ww = w + dw;
            if (hh < 0 || hh >= RESn || ww < 0 || ww >= RESn) continue;
            int widx = (dh + 1) * 3 + (dw + 1);
            short8v wv = *(const short8v*)&Wvlt[widx * 1024 + c0];
            short8v v  = *(const short8v*)&vbuf[((size_t)bi * Nn + hh * RESn + ww) * DHn + c0];
            #pragma unroll
            for (int u = 0; u < 8; ++u)
                acc[u] += su2f(wv[u]) * su2f(v[u]);
        }
    short8v bv = *(const short8v*)&bvl[c0];
    short8v sv = *(const short8v*)&vls[c0];
    short8v hv = *(const short8v*)&vlb[c0];
    size_t off = ((size_t)bi * Nn + n) * DHn + c0;
    short8v ov = *(short8v*)&obuf[off];
    short8v res;
    #pragma unroll
    for (int u = 0; u < 8; ++u) {
        float vl = su2f(sv[u]) * (acc[u] + su2f(bv[u])) + su2f(hv[u]);
        res[u] = f2s(su2f(ov[u]) + vl);
    }
    *(short8v*)&obuf[off] = res;
}

// --------------------------------------------- output projection + BN (MFMA)
__global__ __launch_bounds__(256) void k_outproj_m(
    const bf16* __restrict__ Wp, const bf16* __restrict__ obuf,
    const bf16* __restrict__ bp, const bf16* __restrict__ ps, const bf16* __restrict__ pb,
    void* __restrict__ outv, const int* __restrict__ flag)
{
    __shared__ short ldsA[2048], ldsB[4096];
    const int n0 = blockIdx.x * 128, oc0 = blockIdx.y * 64;
    const int b = blockIdx.z;
    f32x4 acc[2][4] = {};
    gemm_core<2>(Wp, DHn, 384, oc0,
                 obuf + (size_t)b * Nn * DHn, DHn, Nn, n0,
                 DHn, ldsA, ldsB, acc);
    const int isb = *flag;
    EPI_COORDS(2)
    #pragma unroll
    for (int i = 0; i < 2; ++i)
        #pragma unroll
        for (int j = 0; j < 4; ++j) {
            int n = n0 + (wn * 4 + j) * 16 + cl;
            if (n >= Nn) continue;
            int ocb = oc0 + (wm * 2 + i) * 16 + rq * 4;
            #pragma unroll
            for (int r = 0; r < 4; ++r) {
                int oc = ocb + r;
                float a_ = b2f(ps[oc]);
                float be_ = b2f(bp[oc]) * a_ + b2f(pb[oc]);
                float y = a_ * acc[i][j][r] + be_;
                size_t idx = ((size_t)b * CIN + oc) * Nn + n;
                if (isb) ((bf16*)outv)[idx] = f2b(y);
                else     ((float*)outv)[idx] = y;
            }
        }
}

extern "C" void kernel_launch(void* const* d_in, const int* in_sizes, int n_in,
                              void* d_out, int out_size, void* d_ws, size_t ws_size,
                              hipStream_t stream)
{
    char* ws = (char*)d_ws;
    auto align256 = [](size_t v) { return (v + 255) & ~(size_t)255; };

    size_t off = 0;
    size_t off_flag = off;            off = align256(off + 4);
    size_t p_off[26];
    for (int i = 0; i < 26; ++i) { p_off[i] = off; off = align256(off + (size_t)in_sizes[i] * 2); }
    size_t off_mb   = off; off = align256(off + (size_t)8 * Nn * 4);
    size_t off_ab   = off; off = align256(off + (size_t)8 * Nn * AST * 2);
    size_t off_q    = off; off = align256(off + (size_t)Bn * Nn * 256 * 2);
    size_t off_k    = off; off = align256(off + (size_t)Bn * Nn * 256 * 2);
    size_t off_v    = off; off = align256(off + (size_t)Bn * Nn * DHn * 2);
    size_t off_vt   = off; off = align256(off + (size_t)Bn * DHn * AST * 2);
    size_t off_o    = off; off = align256(off + (size_t)Bn * Nn * DHn * 2);
    size_t off_xt   = off; off = align256(off + (size_t)Bn * Nn * CIN * 2);
    size_t off_wqkv = off; off = align256(off + (size_t)1536 * CIN * 2);
    size_t off_al   = off; off = align256(off + (size_t)1536 * 4);
    size_t off_be   = off; off = align256(off + (size_t)1536 * 4);
    size_t off_wvlt = off; off = align256(off + (size_t)9 * 1024 * 2);
    size_t off_cs   = off; off = align256(off + (size_t)Bn * DHn * 4);
    size_t base = off;

    const size_t attn_per_b = (size_t)8 * Nn * AST;      // S bf8
    const size_t p2_per_b   = (size_t)8 * Nn * AST;      // P2 bf8
    int GB = 0;
    const int cand[4] = {8, 4, 2, 1};
    for (int ci = 0; ci < 4; ++ci) {
        if (base + (size_t)cand[ci] * (attn_per_b + p2_per_b) + 512 <= ws_size) { GB = cand[ci]; break; }
    }
    if (!GB) return; // ws too small -> zeros out (diagnostic absmax ~17.4)

    size_t off_attn = base;
    size_t off_p2   = align256(off_attn + (size_t)GB * attn_per_b);

    int*  flag = (int*)(ws + off_flag);
    bf16* Pb[26];
    for (int i = 0; i < 26; ++i) Pb[i] = (bf16*)(ws + p_off[i]);
    float* mb    = (float*)(ws + off_mb);
    bf16* abfull = (bf16*)(ws + off_ab);
    bf16* qbuf  = (bf16*)(ws + off_q);
    bf16* kbuf  = (bf16*)(ws + off_k);
    bf16* vbuf  = (bf16*)(ws + off_v);
    bf16* vt    = (bf16*)(ws + off_vt);
    bf16* obuf  = (bf16*)(ws + off_o);
    bf16* xt    = (bf16*)(ws + off_xt);
    bf16* wqkv  = (bf16*)(ws + off_wqkv);
    float* alf  = (float*)(ws + off_al);
    float* bef  = (float*)(ws + off_be);
    bf16* wvlt  = (bf16*)(ws + off_wvlt);
    float* csum = (float*)(ws + off_cs);
    unsigned char* attn = (unsigned char*)(ws + off_attn);
    unsigned char* p2b  = (unsigned char*)(ws + off_p2);
    const int* idxs = (const int*)d_in[26];

    k_detect<<<1, 64, 0, stream>>>((const unsigned*)d_in[0], flag);

    PtrArgs pa;
    for (int i = 0; i < 26; ++i) pa.p[i] = d_in[i];
    k_prep<<<dim3(288, 4), 256, 0, stream>>>(pa, wqkv, alf, bef, mb, wvlt, flag);

    const int cidx[10] = {14, 15, 16, 17, 19, 20, 21, 22, 23, 24};
    ConvArgs ca;
    for (int i = 0; i < 10; ++i) {
        ca.src[i] = d_in[cidx[i]];
        ca.dstoff[i] = p_off[cidx[i]];
        ca.n[i] = in_sizes[cidx[i]];
    }
    k_convb_all<<<dim3(64, 10), 256, 0, stream>>>(ca, ws, flag);

    bf16 *bvl = Pb[14], *vls = Pb[15], *vlb = Pb[16],
         *W1 = Pb[17], *W2 = Pb[19], *b2v = Pb[20],
         *Wp = Pb[21], *bp = Pb[22], *ps = Pb[23], *pb = Pb[24];

    k_xt<<<dim3(25, 12, 8), 256, 0, stream>>>(d_in[0], xt, flag);
    k_abfull<<<dim3(392), 256, 0, stream>>>(mb, idxs, abfull);

    k_proj_m<<<dim3(7, 12, 8), 256, 0, stream>>>(xt, wqkv, alf, bef, qbuf, kbuf, vbuf);
    k_vt<<<dim3(25, 32, 8), 256, 0, stream>>>(vbuf, vt);
    k_vcolsum<<<dim3(16, 8), 256, 0, stream>>>(vbuf, csum);

    for (int bi0 = 0; bi0 < Bn; bi0 += GB) {
        k_logits_raw<<<dim3(7, 7, GB * 8), 256, 0, stream>>>(qbuf, kbuf, attn, bi0);
        k_softmax_mix<<<dim3(Nn, GB), 256, 0, stream>>>(attn, p2b, abfull, W1, W2);
        k_pv_m<<<dim3(13, 1, GB * 8), 256, 0, stream>>>(p2b, vt, b2v, csum, obuf, bi0);
    }

    k_dwconv_add<<<dim3(1, Nn / 2, 8), 256, 0, stream>>>(vbuf, wvlt, bvl, vls, vlb, obuf);
    k_outproj_m<<<dim3(7, 6, 8), 256, 0, stream>>>(Wp, obuf, bp, ps, pb, d_out, flag);
}

// Round 16
// 228.078 us; speedup vs baseline: 1.0647x; 1.0156x over previous
//
#include <hip/hip_runtime.h>
#include <hip/hip_bf16.h>
#include <hip/hip_fp16.h>

typedef __hip_bfloat16 bf16;
typedef __attribute__((ext_vector_type(8))) short short8v;
typedef __attribute__((ext_vector_type(4))) short short4v;
typedef __attribute__((ext_vector_type(4))) float f32x4;
typedef __attribute__((ext_vector_type(2))) float f32x2;

__device__ __forceinline__ float b2f(bf16 v){ return __bfloat162float(v); }
__device__ __forceinline__ bf16  f2b(float v){ return __float2bfloat16(v); }
__device__ __forceinline__ float su2f(short s){
    unsigned short us = (unsigned short)s;
    return __bfloat162float(*reinterpret_cast<bf16*>(&us));
}
__device__ __forceinline__ short f2s(float v){
    bf16 b = __float2bfloat16(v);
    return *reinterpret_cast<short*>(&b);
}
__device__ __forceinline__ float ldf(const void* t, size_t i, int isb){
    return isb ? b2f(((const bf16*)t)[i]) : ((const float*)t)[i];
}

// ---- bf8 (e5m2) codec: HW cvt_pk if available, else f16-path software RNE ----
__device__ __forceinline__ unsigned f2bf8_sw(float f){
    unsigned short h = __half_as_ushort(__float2half(f));
    unsigned lsb = (h >> 8) & 1u, rb = (h >> 7) & 1u, st = (h & 0x7Fu) ? 1u : 0u;
    return ((unsigned)(h >> 8) + (rb & (st | lsb))) & 0xFFu;
}
__device__ __forceinline__ float bf82f_sw(unsigned b){
    return __half2float(__ushort_as_half((unsigned short)(b << 8)));
}
__device__ __forceinline__ unsigned pack4_bf8(float a0, float a1, float a2, float a3){
#if __has_builtin(__builtin_amdgcn_cvt_pk_bf8_f32)
    int u = __builtin_amdgcn_cvt_pk_bf8_f32(a0, a1, 0, false);
    u = __builtin_amdgcn_cvt_pk_bf8_f32(a2, a3, u, true);
    return (unsigned)u;
#else
    return f2bf8_sw(a0) | (f2bf8_sw(a1) << 8) | (f2bf8_sw(a2) << 16) | (f2bf8_sw(a3) << 24);
#endif
}
__device__ __forceinline__ unsigned f2bf8_1(float f){
#if __has_builtin(__builtin_amdgcn_cvt_pk_bf8_f32)
    return (unsigned)__builtin_amdgcn_cvt_pk_bf8_f32(f, f, 0, false) & 0xFFu;
#else
    return f2bf8_sw(f);
#endif
}
__device__ __forceinline__ void unpack4_bf8(unsigned u, float* o){
#if __has_builtin(__builtin_amdgcn_cvt_pk_f32_bf8)
    f32x2 lo = __builtin_amdgcn_cvt_pk_f32_bf8((int)u, false);
    f32x2 hi = __builtin_amdgcn_cvt_pk_f32_bf8((int)u, true);
    o[0] = lo[0]; o[1] = lo[1]; o[2] = hi[0]; o[3] = hi[1];
#else
    o[0] = bf82f_sw(u & 0xFFu);         o[1] = bf82f_sw((u >> 8) & 0xFFu);
    o[2] = bf82f_sw((u >> 16) & 0xFFu); o[3] = bf82f_sw((u >> 24) & 0xFFu);
#endif
}
__device__ __forceinline__ void unpack4_bf8_pk(unsigned u, f32x2& lo, f32x2& hi){
#if __has_builtin(__builtin_amdgcn_cvt_pk_f32_bf8)
    lo = __builtin_amdgcn_cvt_pk_f32_bf8((int)u, false);
    hi = __builtin_amdgcn_cvt_pk_f32_bf8((int)u, true);
#else
    lo = f32x2{bf82f_sw(u & 0xFFu), bf82f_sw((u >> 8) & 0xFFu)};
    hi = f32x2{bf82f_sw((u >> 16) & 0xFFu), bf82f_sw((u >> 24) & 0xFFu)};
#endif
}

constexpr int Bn = 8, CIN = 384, RESn = 28, Nn = 784, DHn = 1024;
constexpr int AST = 800;   // padded attn/vt K-stride (25*32)

// ---------------------------------------------------- async global->LDS 16B
__device__ __forceinline__ void gload16(const void* g, void* l)
{
    __builtin_amdgcn_global_load_lds(
        (const __attribute__((address_space(1))) void*)g,
        (__attribute__((address_space(3))) void*)l, 16, 0, 0);
}

// -------------------------------------------------- dtype detector (1 thread)
__global__ void k_detect(const unsigned* __restrict__ xw, int* __restrict__ flag)
{
    if (blockIdx.x == 0 && threadIdx.x == 0) {
        int cnt = 0;
        for (int i = 0; i < 256; ++i) {
            unsigned lo = xw[i] & 0xFFFFu;
            int e = (int)((lo >> 7) & 0xFF);
            if (e >= 112 && e <= 132) ++cnt;
        }
        *flag = (cnt >= 128) ? 1 : 0;
    }
}

// -- fused prep: wpack | affine | mixbias | dw-weight transpose (reads d_in raw)
struct PtrArgs { const void* p[26]; };
__global__ __launch_bounds__(256) void k_prep(PtrArgs a, bf16* __restrict__ Wqkv,
                                              float* __restrict__ al, float* __restrict__ be,
                                              float* __restrict__ mb, bf16* __restrict__ Wvlt,
                                              const int* __restrict__ flag)
{
    const int isb = *flag;
    const int tid = threadIdx.x;
    const int role = blockIdx.y;
    if (role == 0) {
        int stride = gridDim.x * 256;
        for (int e = blockIdx.x * 256 + tid; e < 1536 * 384; e += stride) {
            int co = e / 384, k = e % 384;
            const void* src; int lc;
            if (co < 256)      { src = a.p[1]; lc = co; }
            else if (co < 512) { src = a.p[5]; lc = co - 256; }
            else               { src = a.p[9]; lc = co - 512; }
            Wqkv[e] = f2b(ldf(src, (size_t)lc * 384 + k, isb));
        }
    } else if (role == 1) {
        int co = blockIdx.x * 256 + tid;
        if (co < 1536) {
            const void *b_, *s_, *h_; int lc;
            if (co < 256)      { b_ = a.p[2];  s_ = a.p[3];  h_ = a.p[4];  lc = co; }
            else if (co < 512) { b_ = a.p[6];  s_ = a.p[7];  h_ = a.p[8];  lc = co - 256; }
            else               { b_ = a.p[10]; s_ = a.p[11]; h_ = a.p[12]; lc = co - 512; }
            float aa = ldf(s_, lc, isb);
            al[co] = aa;
            be[co] = ldf(b_, lc, isb) * aa + ldf(h_, lc, isb);
        }
    } else if (role == 2) {
        int i = blockIdx.x * 256 + tid;
        if (i < 8 * Nn) {
            int g = i / Nn, p = i % Nn;
            float acc = ldf(a.p[18], g, isb);
            #pragma unroll
            for (int h = 0; h < 8; ++h)
                acc += ldf(a.p[17], g * 8 + h, isb) * ldf(a.p[25], (size_t)h * Nn + p, isb);
            mb[i] = acc;
        }
    } else {
        int e = blockIdx.x * 256 + tid;   // Wvl [1024][9] -> Wvlt [9][1024]
        if (e < 1024 * 9) {
            int c = e / 9, tap = e % 9;
            Wvlt[tap * 1024 + c] = f2b(ldf(a.p[13], e, isb));
        }
    }
}

// ------------------------------------- convert needed tensors -> bf16
struct ConvArgs { const void* src[10]; unsigned long long dstoff[10]; int n[10]; };
__global__ void k_convb_all(ConvArgs a, char* __restrict__ ws, const int* __restrict__ flag)
{
    int i = blockIdx.y;
    int n = a.n[i];
    const void* s = a.src[i];
    bf16* d = (bf16*)(ws + a.dstoff[i]);
    int isb = *flag;
    int stride = gridDim.x * blockDim.x;
    for (int t = blockIdx.x * blockDim.x + threadIdx.x; t < n; t += stride)
        d[t] = isb ? ((const bf16*)s)[t] : f2b(((const float*)s)[t]);
}

// ------------------- expand mb through idx: abfull[g][n][m] (b-independent)
__global__ __launch_bounds__(256) void k_abfull(
    const float* __restrict__ mb, const int* __restrict__ idxs,
    bf16* __restrict__ abfull)
{
    __shared__ float mbs[8][Nn];
    const int tid = threadIdx.x;
    for (int i = tid; i < 8 * Nn; i += 256) ((float*)mbs)[i] = mb[i];
    __syncthreads();
    const int nstart = blockIdx.x * 2;
    for (int n = nstart; n < nstart + 2; ++n) {
        for (int m = tid; m < Nn; m += 256) {
            int id = idxs[(size_t)n * Nn + m];
            #pragma unroll
            for (int g = 0; g < 8; ++g)
                abfull[((size_t)g * Nn + n) * AST + m] = f2b(mbs[g][id]);
        }
    }
}

// ------------- x transpose + inline convert: [b][384][784] -> [b][784][384]
__global__ __launch_bounds__(256) void k_xt(const void* __restrict__ xr, bf16* __restrict__ xt,
                                            const int* __restrict__ flag)
{
    const int isb = *flag;
    __shared__ bf16 t[32][33];
    int b = blockIdx.z, n0 = blockIdx.x * 32, c0 = blockIdx.y * 32;
    int tid = threadIdx.x;
    for (int i = tid; i < 1024; i += 256) {
        int r = i >> 5, c = i & 31;
        int n = n0 + c;
        t[r][c] = (n < Nn) ? f2b(ldf(xr, ((size_t)b * CIN + c0 + r) * Nn + n, isb)) : f2b(0.f);
    }
    __syncthreads();
    for (int i = tid; i < 1024; i += 256) {
        int r = i >> 5, c = i & 31;
        int n = n0 + r;
        if (n < Nn) xt[((size_t)b * Nn + n) * CIN + c0 + c] = t[c][r];
    }
}

// ----- merged: v transpose (x<25) | v colsum (x==25, y<16); both read vbuf
__global__ __launch_bounds__(256) void k_vt_cs(const bf16* __restrict__ vbuf,
                                               bf16* __restrict__ vt,
                                               float* __restrict__ colsum)
{
    const int b = blockIdx.z;
    const int tid = threadIdx.x;
    if (blockIdx.x < 25) {
        __shared__ bf16 t[32][33];
        int n0 = blockIdx.x * 32, c0 = blockIdx.y * 32;
        for (int i = tid; i < 1024; i += 256) {
            int r = i >> 5, c = i & 31;
            int n = n0 + r;
            t[r][c] = (n < Nn) ? vbuf[((size_t)b * Nn + n) * DHn + c0 + c] : f2b(0.f);
        }
        __syncthreads();
        for (int i = tid; i < 1024; i += 256) {
            int r = i >> 5, c = i & 31;
            int n = n0 + c;   // n < 800 always
            vt[((size_t)b * DHn + c0 + r) * AST + n] = t[c][r];
        }
    } else if (blockIdx.y < 16) {
        __shared__ float red[4][64];
        const int c0 = blockIdx.y * 64;
        const int cl = tid & 63, part = tid >> 6;
        float s = 0.f;
        const int nst = part * 196;
        for (int n = nst; n < nst + 196; ++n)
            s += b2f(vbuf[((size_t)b * Nn + n) * DHn + c0 + cl]);
        red[part][cl] = s;
        __syncthreads();
        if (tid < 64)
            colsum[(size_t)b * DHn + c0 + tid] = red[0][tid] + red[1][tid] + red[2][tid] + red[3][tid];
    }
}

// -------------------- frag-linear staging: 64 rows x 32 k of a K-contig matrix
__device__ __forceinline__ void stage64x32(const bf16* __restrict__ src,
    int row0, int row_lim, int k0, int k_lim, int ld, short* lds, int tid)
{
    int rsub = ((tid >> 6) << 4) | (tid & 15);
    int q    = (tid >> 4) & 3;
    int row = row0 + rsub; row = row < row_lim ? row : row_lim - 1;
    gload16((const short*)src + (size_t)row * ld + k0 + q * 8,
            lds + (size_t)(((rsub >> 4) * 4 + q) * 16 + (rsub & 15)) * 8);
}

// ------------------- generic MFMA core: tile (MI*32) x 128, BK=32, gload_lds
template<int MI>
__device__ __forceinline__ void gemm_core(
    const bf16* __restrict__ A, int lda, int rowsA, int arow0,
    const bf16* __restrict__ B, int ldb, int rowsB, int brow0,
    int K, short* ldsA, short* ldsB, f32x4 (&acc)[MI][4])
{
    const int tid  = threadIdx.x;
    const int lane = tid & 63;
    const int wm   = tid >> 7, wn = (tid >> 6) & 1;
    const short8v* A8 = (const short8v*)ldsA;
    const short8v* B8 = (const short8v*)ldsB;

    for (int k0 = 0; k0 < K; k0 += 32) {
        __syncthreads();
        #pragma unroll
        for (int c = 0; c < MI / 2; ++c)
            stage64x32(A, arow0 + c * 64, rowsA, k0, K, lda, ldsA + c * 2048, tid);
        #pragma unroll
        for (int c = 0; c < 2; ++c)
            stage64x32(B, brow0 + c * 64, rowsB, k0, K, ldb, ldsB + c * 2048, tid);
        __syncthreads();
        short8v a[MI], bb[4];
        #pragma unroll
        for (int i = 0; i < MI; ++i) a[i] = A8[(wm * MI + i) * 64 + lane];
        #pragma unroll
        for (int j = 0; j < 4; ++j) bb[j] = B8[(wn * 4 + j) * 64 + lane];
        #pragma unroll
        for (int i = 0; i < MI; ++i)
            #pragma unroll
            for (int j = 0; j < 4; ++j)
                acc[i][j] = __builtin_amdgcn_mfma_f32_16x16x32_bf16(a[i], bb[j], acc[i][j], 0, 0, 0);
    }
}

#define EPI_COORDS(MI)                                      \
    const int tid  = threadIdx.x;                           \
    const int lane = tid & 63;                              \
    const int wm   = tid >> 7, wn = (tid >> 6) & 1;         \
    const int rq   = lane >> 4, cl = lane & 15; (void)rq;

// --------------------------------------------- q/k/v projection + BN (MFMA)
__global__ __launch_bounds__(256) void k_proj_m(
    const bf16* __restrict__ xt, const bf16* __restrict__ Wqkv,
    const float* __restrict__ al, const float* __restrict__ be,
    bf16* __restrict__ qbuf, bf16* __restrict__ kbuf, bf16* __restrict__ vbuf)
{
    __shared__ short ldsA[4096], ldsB[4096];
    const int n0 = blockIdx.x * 128, co0 = blockIdx.y * 128;
    const int b = blockIdx.z;
    f32x4 acc[4][4] = {};
    gemm_core<4>(xt + (size_t)b * Nn * CIN, CIN, Nn, n0,
                 Wqkv, CIN, 1536, co0, CIN, ldsA, ldsB, acc);
    EPI_COORDS(4)
    #pragma unroll
    for (int i = 0; i < 4; ++i)
        #pragma unroll
        for (int j = 0; j < 4; ++j) {
            int co = co0 + (wn * 4 + j) * 16 + cl;
            float a_ = al[co], bb_ = be[co];
            int nb = n0 + (wm * 4 + i) * 16 + rq * 4;
            #pragma unroll
            for (int r = 0; r < 4; ++r) {
                int n = nb + r;
                if (n >= Nn) continue;
                float y = a_ * acc[i][j][r] + bb_;
                if (co < 256)      qbuf[((size_t)b * Nn + n) * 256 + co]       = f2b(y);
                else if (co < 512) kbuf[((size_t)b * Nn + n) * 256 + (co-256)] = f2b(y);
                else               vbuf[((size_t)b * Nn + n) * DHn + (co-512)] = f2b(y);
            }
        }
}

// ------------- raw per-head logits: qk[h][n][m] -> bf8, K=32 (no mix/bias)
__global__ __launch_bounds__(256) void k_logits_raw(
    const bf16* __restrict__ qbuf, const bf16* __restrict__ kbuf,
    unsigned char* __restrict__ attn, int bi0)
{
    __shared__ short ldsA[4096], ldsB[4096];
    const int n0 = blockIdx.x * 128, m0 = blockIdx.y * 128;
    const int z = blockIdx.z, h = z & 7, bloc = z >> 3, b = bi0 + bloc;
    f32x4 acc[4][4] = {};
    gemm_core<4>(qbuf + (size_t)b * Nn * 256 + h * 32, 256, Nn, n0,
                 kbuf + (size_t)b * Nn * 256 + h * 32, 256, Nn, m0,
                 32, ldsA, ldsB, acc);
    unsigned char* arow = attn + (size_t)(bloc * 8 + h) * Nn * AST;
    EPI_COORDS(4)
    #pragma unroll
    for (int i = 0; i < 4; ++i)
        #pragma unroll
        for (int j = 0; j < 4; ++j) {
            int m = m0 + (wn * 4 + j) * 16 + cl;
            if (m >= Nn) continue;
            int nb = n0 + (wm * 4 + i) * 16 + rq * 4;
            #pragma unroll
            for (int r = 0; r < 4; ++r) {
                int n = nb + r;
                if (n < Nn) arow[(size_t)n * AST + m] = (unsigned char)f2bf8_1(acc[i][j][r]);
            }
        }
}

// --- fused: th1 mix (+abfull) + softmax (no-max) + th2 mix (NO b2) -> bf8 P2
// packed f32x2 math throughout (v_pk_fma)
__global__ __launch_bounds__(256) void k_softmax_mix(
    const unsigned char* __restrict__ attn_all, unsigned char* __restrict__ p2_all,
    const bf16* __restrict__ abfull,
    const bf16* __restrict__ W1, const bf16* __restrict__ W2)
{
    const int n = blockIdx.x, bloc = blockIdx.y;
    const int tid = threadIdx.x;
    const unsigned char* base = attn_all + (size_t)bloc * 8 * Nn * AST;
    unsigned char* p2b = p2_all + (size_t)bloc * 8 * Nn * AST;
    __shared__ float w1s[64], w2s[64], lis[8], wred[4][8];
    if (tid < 64) { w1s[tid] = b2f(W1[tid]) * 0.17677669529663687f; w2s[tid] = b2f(W2[tid]); }
    __syncthreads();

    const bool live = tid < 196;
    const int m0 = (live ? tid : 195) * 4;

    f32x2 raw2[8][2];
    #pragma unroll
    for (int h = 0; h < 8; ++h) {
        unsigned u = *(const unsigned*)(base + ((size_t)h * Nn + n) * AST + m0);
        unpack4_bf8_pk(u, raw2[h][0], raw2[h][1]);
    }

    f32x2 out2[8][2];
    #pragma unroll
    for (int g = 0; g < 8; ++g) {
        short4v bv = *(const short4v*)(abfull + ((size_t)g * Nn + n) * AST + m0);
        f32x2 a0 = {su2f(bv[0]), su2f(bv[1])};
        f32x2 a1 = {su2f(bv[2]), su2f(bv[3])};
        #pragma unroll
        for (int h = 0; h < 8; ++h) {
            float w = w1s[g * 8 + h];
            f32x2 wv = {w, w};
            a0 += raw2[h][0] * wv;
            a1 += raw2[h][1] * wv;
        }
        f32x2 e0, e1;
        e0[0] = __expf(fminf(a0[0], 60.f));
        e0[1] = __expf(fminf(a0[1], 60.f));
        e1[0] = __expf(fminf(a1[0], 60.f));
        e1[1] = __expf(fminf(a1[1], 60.f));
        out2[g][0] = e0;
        out2[g][1] = e1;
        float s = live ? (e0[0] + e0[1]) + (e1[0] + e1[1]) : 0.f;
        #pragma unroll
        for (int sh = 32; sh > 0; sh >>= 1) s += __shfl_xor(s, sh, 64);
        if ((tid & 63) == 0) wred[tid >> 6][g] = s;
    }
    __syncthreads();
    if (tid < 8)
        lis[tid] = 1.f / (wred[0][tid] + wred[1][tid] + wred[2][tid] + wred[3][tid]);
    __syncthreads();

    #pragma unroll
    for (int h = 0; h < 8; ++h) {
        float lh = lis[h];
        f32x2 lv = {lh, lh};
        out2[h][0] *= lv;
        out2[h][1] *= lv;
    }
    if (live) {
        #pragma unroll
        for (int g = 0; g < 8; ++g) {
            f32x2 acc0 = {0.f, 0.f};
            f32x2 acc1 = {0.f, 0.f};
            #pragma unroll
            for (int h = 0; h < 8; ++h) {
                float w = w2s[g * 8 + h];
                f32x2 wv = {w, w};
                acc0 += out2[h][0] * wv;
                acc1 += out2[h][1] * wv;
            }
            unsigned u = pack4_bf8(acc0[0], acc0[1], acc1[0], acc1[1]);
            *(unsigned*)(p2b + ((size_t)g * Nn + n) * AST + m0) = u;
        }
    }
}

// ------- PV: obuf[b][n][c] = P2mix(bf8) . v  + b2[g]*colsum_v  (MFMA bf16)
__global__ __launch_bounds__(256) void k_pv_m(
    const unsigned char* __restrict__ p2, const bf16* __restrict__ vt,
    const bf16* __restrict__ b2v, const float* __restrict__ colsum,
    bf16* __restrict__ obuf, int bi0)
{
    __shared__ short ldsA[2048], ldsB[4096];
    const int tid = threadIdx.x;
    const int n0 = blockIdx.x * 64;
    const int z = blockIdx.z, g = z & 7, bloc = z >> 3, b = bi0 + bloc;
    const unsigned char* Ap = p2 + (size_t)(bloc * 8 + g) * Nn * AST;
    const bf16* Bv = vt + ((size_t)b * DHn + g * 128) * AST;
    const int lane = tid & 63;
    const int wm = tid >> 7, wn = (tid >> 6) & 1;
    const int rsub = ((tid >> 6) << 4) | (tid & 15);
    const int q = (tid >> 4) & 3;
    const short8v* A8 = (const short8v*)ldsA;
    const short8v* B8 = (const short8v*)ldsB;
    f32x4 acc[2][4] = {};

    for (int k0 = 0; k0 < AST; k0 += 32) {
        __syncthreads();
        {   // A stage: load 8 bf8 bytes, HW-decode -> bf16 frag slot
            int row = n0 + rsub; row = row < Nn ? row : Nn - 1;
            const unsigned char* src = Ap + (size_t)row * AST + k0 + q * 8;
            unsigned lo = *(const unsigned*)src;
            unsigned hi = *(const unsigned*)(src + 4);
            float d0[4], d1[4];
            unpack4_bf8(lo, d0);
            unpack4_bf8(hi, d1);
            short8v o;
            #pragma unroll
            for (int j = 0; j < 4; ++j) { o[j] = f2s(d0[j]); o[4 + j] = f2s(d1[j]); }
            ((short8v*)ldsA)[((rsub >> 4) * 4 + q) * 16 + (rsub & 15)] = o;
        }
        stage64x32(Bv, 0,  128, k0, AST, AST, ldsB, tid);
        stage64x32(Bv, 64, 128, k0, AST, AST, ldsB + 2048, tid);
        __syncthreads();
        short8v a[2], bb[4];
        #pragma unroll
        for (int i = 0; i < 2; ++i) a[i] = A8[(wm * 2 + i) * 64 + lane];
        #pragma unroll
        for (int j = 0; j < 4; ++j) bb[j] = B8[(wn * 4 + j) * 64 + lane];
        #pragma unroll
        for (int i = 0; i < 2; ++i)
            #pragma unroll
            for (int j = 0; j < 4; ++j)
                acc[i][j] = __builtin_amdgcn_mfma_f32_16x16x32_bf16(a[i], bb[j], acc[i][j], 0, 0, 0);
    }

    bf16* ob = obuf + (size_t)b * Nn * DHn + g * 128;
    const float b2g = b2f(b2v[g]);
    const int rq = lane >> 4, cl = lane & 15;
    #pragma unroll
    for (int i = 0; i < 2; ++i)
        #pragma unroll
        for (int j = 0; j < 4; ++j) {
            int d = (wn * 4 + j) * 16 + cl;
            float cs = b2g * colsum[(size_t)b * DHn + g * 128 + d];
            int nb = n0 + (wm * 2 + i) * 16 + rq * 4;
            #pragma unroll
            for (int r = 0; r < 4; ++r) {
                int n = nb + r;
                if (n < Nn) ob[(size_t)n * DHn + d] = f2b(acc[i][j][r] + cs);
            }
        }
}

// ---- depthwise conv+BN, ADDS into obuf (o += vl), fully vectorized weights
__global__ __launch_bounds__(256) void k_dwconv_add(
    const bf16* __restrict__ vbuf, const bf16* __restrict__ Wvlt,
    const bf16* __restrict__ bvl, const bf16* __restrict__ vls, const bf16* __restrict__ vlb,
    bf16* __restrict__ obuf)
{
    const int t = threadIdx.x;
    const int n = blockIdx.y * 2 + (t >> 7);
    const int bi = blockIdx.z;
    const int c0 = (t & 127) * 8;
    const int h = n / RESn, w = n % RESn;
    float acc[8] = {};
    #pragma unroll
    for (int dh = -1; dh <= 1; ++dh)
        #pragma unroll
        for (int dw = -1; dw <= 1; ++dw) {
            int hh = h + dh, ww = w + dw;
            if (hh < 0 || hh >= RESn || ww < 0 || ww >= RESn) continue;
            int widx = (dh + 1) * 3 + (dw + 1);
            short8v wv = *(const short8v*)&Wvlt[widx * 1024 + c0];
            short8v v  = *(const short8v*)&vbuf[((size_t)bi * Nn + hh * RESn + ww) * DHn + c0];
            #pragma unroll
            for (int u = 0; u < 8; ++u)
                acc[u] += su2f(wv[u]) * su2f(v[u]);
        }
    short8v bv = *(const short8v*)&bvl[c0];
    short8v sv = *(const short8v*)&vls[c0];
    short8v hv = *(const short8v*)&vlb[c0];
    size_t off = ((size_t)bi * Nn + n) * DHn + c0;
    short8v ov = *(short8v*)&obuf[off];
    short8v res;
    #pragma unroll
    for (int u = 0; u < 8; ++u) {
        float vl = su2f(sv[u]) * (acc[u] + su2f(bv[u])) + su2f(hv[u]);
        res[u] = f2s(su2f(ov[u]) + vl);
    }
    *(short8v*)&obuf[off] = res;
}

// --------------------------------------------- output projection + BN (MFMA)
__global__ __launch_bounds__(256) void k_outproj_m(
    const bf16* __restrict__ Wp, const bf16* __restrict__ obuf,
    const bf16* __restrict__ bp, const bf16* __restrict__ ps, const bf16* __restrict__ pb,
    void* __restrict__ outv, const int* __restrict__ flag)
{
    __shared__ short ldsA[2048], ldsB[4096];
    const int n0 = blockIdx.x * 128, oc0 = blockIdx.y * 64;
    const int b = blockIdx.z;
    f32x4 acc[2][4] = {};
    gemm_core<2>(Wp, DHn, 384, oc0,
                 obuf + (size_t)b * Nn * DHn, DHn, Nn, n0,
                 DHn, ldsA, ldsB, acc);
    const int isb = *flag;
    EPI_COORDS(2)
    #pragma unroll
    for (int i = 0; i < 2; ++i)
        #pragma unroll
        for (int j = 0; j < 4; ++j) {
            int n = n0 + (wn * 4 + j) * 16 + cl;
            if (n >= Nn) continue;
            int ocb = oc0 + (wm * 2 + i) * 16 + rq * 4;
            #pragma unroll
            for (int r = 0; r < 4; ++r) {
                int oc = ocb + r;
                float a_ = b2f(ps[oc]);
                float be_ = b2f(bp[oc]) * a_ + b2f(pb[oc]);
                float y = a_ * acc[i][j][r] + be_;
                size_t idx = ((size_t)b * CIN + oc) * Nn + n;
                if (isb) ((bf16*)outv)[idx] = f2b(y);
                else     ((float*)outv)[idx] = y;
            }
        }
}

extern "C" void kernel_launch(void* const* d_in, const int* in_sizes, int n_in,
                              void* d_out, int out_size, void* d_ws, size_t ws_size,
                              hipStream_t stream)
{
    char* ws = (char*)d_ws;
    auto align256 = [](size_t v) { return (v + 255) & ~(size_t)255; };

    size_t off = 0;
    size_t off_flag = off;            off = align256(off + 4);
    size_t p_off[26];
    for (int i = 0; i < 26; ++i) { p_off[i] = off; off = align256(off + (size_t)in_sizes[i] * 2); }
    size_t off_mb   = off; off = align256(off + (size_t)8 * Nn * 4);
    size_t off_ab   = off; off = align256(off + (size_t)8 * Nn * AST * 2);
    size_t off_q    = off; off = align256(off + (size_t)Bn * Nn * 256 * 2);
    size_t off_k    = off; off = align256(off + (size_t)Bn * Nn * 256 * 2);
    size_t off_v    = off; off = align256(off + (size_t)Bn * Nn * DHn * 2);
    size_t off_vt   = off; off = align256(off + (size_t)Bn * DHn * AST * 2);
    size_t off_o    = off; off = align256(off + (size_t)Bn * Nn * DHn * 2);
    size_t off_xt   = off; off = align256(off + (size_t)Bn * Nn * CIN * 2);
    size_t off_wqkv = off; off = align256(off + (size_t)1536 * CIN * 2);
    size_t off_al   = off; off = align256(off + (size_t)1536 * 4);
    size_t off_be   = off; off = align256(off + (size_t)1536 * 4);
    size_t off_wvlt = off; off = align256(off + (size_t)9 * 1024 * 2);
    size_t off_cs   = off; off = align256(off + (size_t)Bn * DHn * 4);
    size_t base = off;

    const size_t attn_per_b = (size_t)8 * Nn * AST;      // S bf8
    const size_t p2_per_b   = (size_t)8 * Nn * AST;      // P2 bf8
    int GB = 0;
    const int cand[4] = {8, 4, 2, 1};
    for (int ci = 0; ci < 4; ++ci) {
        if (base + (size_t)cand[ci] * (attn_per_b + p2_per_b) + 512 <= ws_size) { GB = cand[ci]; break; }
    }
    if (!GB) return; // ws too small -> zeros out (diagnostic absmax ~17.4)

    size_t off_attn = base;
    size_t off_p2   = align256(off_attn + (size_t)GB * attn_per_b);

    int*  flag = (int*)(ws + off_flag);
    bf16* Pb[26];
    for (int i = 0; i < 26; ++i) Pb[i] = (bf16*)(ws + p_off[i]);
    float* mb    = (float*)(ws + off_mb);
    bf16* abfull = (bf16*)(ws + off_ab);
    bf16* qbuf  = (bf16*)(ws + off_q);
    bf16* kbuf  = (bf16*)(ws + off_k);
    bf16* vbuf  = (bf16*)(ws + off_v);
    bf16* vt    = (bf16*)(ws + off_vt);
    bf16* obuf  = (bf16*)(ws + off_o);
    bf16* xt    = (bf16*)(ws + off_xt);
    bf16* wqkv  = (bf16*)(ws + off_wqkv);
    float* alf  = (float*)(ws + off_al);
    float* bef  = (float*)(ws + off_be);
    bf16* wvlt  = (bf16*)(ws + off_wvlt);
    float* csum = (float*)(ws + off_cs);
    unsigned char* attn = (unsigned char*)(ws + off_attn);
    unsigned char* p2b  = (unsigned char*)(ws + off_p2);
    const int* idxs = (const int*)d_in[26];

    k_detect<<<1, 64, 0, stream>>>((const unsigned*)d_in[0], flag);

    PtrArgs pa;
    for (int i = 0; i < 26; ++i) pa.p[i] = d_in[i];
    k_prep<<<dim3(288, 4), 256, 0, stream>>>(pa, wqkv, alf, bef, mb, wvlt, flag);

    const int cidx[10] = {14, 15, 16, 17, 19, 20, 21, 22, 23, 24};
    ConvArgs ca;
    for (int i = 0; i < 10; ++i) {
        ca.src[i] = d_in[cidx[i]];
        ca.dstoff[i] = p_off[cidx[i]];
        ca.n[i] = in_sizes[cidx[i]];
    }
    k_convb_all<<<dim3(64, 10), 256, 0, stream>>>(ca, ws, flag);

    bf16 *bvl = Pb[14], *vls = Pb[15], *vlb = Pb[16],
         *W1 = Pb[17], *W2 = Pb[19], *b2v = Pb[20],
         *Wp = Pb[21], *bp = Pb[22], *ps = Pb[23], *pb = Pb[24];

    k_xt<<<dim3(25, 12, 8), 256, 0, stream>>>(d_in[0], xt, flag);
    k_abfull<<<dim3(392), 256, 0, stream>>>(mb, idxs, abfull);

    k_proj_m<<<dim3(7, 12, 8), 256, 0, stream>>>(xt, wqkv, alf, bef, qbuf, kbuf, vbuf);
    k_vt_cs<<<dim3(26, 32, 8), 256, 0, stream>>>(vbuf, vt, csum);

    for (int bi0 = 0; bi0 < Bn; bi0 += GB) {
        k_logits_raw<<<dim3(7, 7, GB * 8), 256, 0, stream>>>(qbuf, kbuf, attn, bi0);
        k_softmax_mix<<<dim3(Nn, GB), 256, 0, stream>>>(attn, p2b, abfull, W1, W2);
        k_pv_m<<<dim3(13, 1, GB * 8), 256, 0, stream>>>(p2b, vt, b2v, csum, obuf, bi0);
    }

    k_dwconv_add<<<dim3(1, Nn / 2, 8), 256, 0, stream>>>(vbuf, wvlt, bvl, vls, vlb, obuf);
    k_outproj_m<<<dim3(7, 6, 8), 256, 0, stream>>>(Wp, obuf, bp, ps, pb, d_out, flag);
}

// Round 17
// 224.209 us; speedup vs baseline: 1.0831x; 1.0173x over previous
//
#include <hip/hip_runtime.h>
#include <hip/hip_bf16.h>
#include <hip/hip_fp16.h>

typedef __hip_bfloat16 bf16;
typedef __attribute__((ext_vector_type(8))) short short8v;
typedef __attribute__((ext_vector_type(4))) short short4v;
typedef __attribute__((ext_vector_type(4))) float f32x4;
typedef __attribute__((ext_vector_type(2))) float f32x2;

__device__ __forceinline__ float b2f(bf16 v){ return __bfloat162float(v); }
__device__ __forceinline__ bf16  f2b(float v){ return __float2bfloat16(v); }
__device__ __forceinline__ float su2f(short s){
    unsigned short us = (unsigned short)s;
    return __bfloat162float(*reinterpret_cast<bf16*>(&us));
}
__device__ __forceinline__ short f2s(float v){
    bf16 b = __float2bfloat16(v);
    return *reinterpret_cast<short*>(&b);
}
__device__ __forceinline__ float ldf(const void* t, size_t i, int isb){
    return isb ? b2f(((const bf16*)t)[i]) : ((const float*)t)[i];
}

// ---- bf8 (e5m2) codec: HW cvt_pk if available, else f16-path software RNE ----
__device__ __forceinline__ unsigned f2bf8_sw(float f){
    unsigned short h = __half_as_ushort(__float2half(f));
    unsigned lsb = (h >> 8) & 1u, rb = (h >> 7) & 1u, st = (h & 0x7Fu) ? 1u : 0u;
    return ((unsigned)(h >> 8) + (rb & (st | lsb))) & 0xFFu;
}
__device__ __forceinline__ float bf82f_sw(unsigned b){
    return __half2float(__ushort_as_half((unsigned short)(b << 8)));
}
__device__ __forceinline__ unsigned pack4_bf8(float a0, float a1, float a2, float a3){
#if __has_builtin(__builtin_amdgcn_cvt_pk_bf8_f32)
    int u = __builtin_amdgcn_cvt_pk_bf8_f32(a0, a1, 0, false);
    u = __builtin_amdgcn_cvt_pk_bf8_f32(a2, a3, u, true);
    return (unsigned)u;
#else
    return f2bf8_sw(a0) | (f2bf8_sw(a1) << 8) | (f2bf8_sw(a2) << 16) | (f2bf8_sw(a3) << 24);
#endif
}
__device__ __forceinline__ unsigned f2bf8_1(float f){
#if __has_builtin(__builtin_amdgcn_cvt_pk_bf8_f32)
    return (unsigned)__builtin_amdgcn_cvt_pk_bf8_f32(f, f, 0, false) & 0xFFu;
#else
    return f2bf8_sw(f);
#endif
}
__device__ __forceinline__ void unpack4_bf8(unsigned u, float* o){
#if __has_builtin(__builtin_amdgcn_cvt_pk_f32_bf8)
    f32x2 lo = __builtin_amdgcn_cvt_pk_f32_bf8((int)u, false);
    f32x2 hi = __builtin_amdgcn_cvt_pk_f32_bf8((int)u, true);
    o[0] = lo[0]; o[1] = lo[1]; o[2] = hi[0]; o[3] = hi[1];
#else
    o[0] = bf82f_sw(u & 0xFFu);         o[1] = bf82f_sw((u >> 8) & 0xFFu);
    o[2] = bf82f_sw((u >> 16) & 0xFFu); o[3] = bf82f_sw((u >> 24) & 0xFFu);
#endif
}
__device__ __forceinline__ void unpack4_bf8_pk(unsigned u, f32x2& lo, f32x2& hi){
#if __has_builtin(__builtin_amdgcn_cvt_pk_f32_bf8)
    lo = __builtin_amdgcn_cvt_pk_f32_bf8((int)u, false);
    hi = __builtin_amdgcn_cvt_pk_f32_bf8((int)u, true);
#else
    lo = f32x2{bf82f_sw(u & 0xFFu), bf82f_sw((u >> 8) & 0xFFu)};
    hi = f32x2{bf82f_sw((u >> 16) & 0xFFu), bf82f_sw((u >> 24) & 0xFFu)};
#endif
}

constexpr int Bn = 8, CIN = 384, RESn = 28, Nn = 784, DHn = 1024;
constexpr int AST = 800;   // padded attn/vt K-stride (25*32)

// ---------------------------------------------------- async global->LDS 16B
__device__ __forceinline__ void gload16(const void* g, void* l)
{
    __builtin_amdgcn_global_load_lds(
        (const __attribute__((address_space(1))) void*)g,
        (__attribute__((address_space(3))) void*)l, 16, 0, 0);
}

// -------------------------------------------------- dtype detector (1 thread)
__global__ void k_detect(const unsigned* __restrict__ xw, int* __restrict__ flag)
{
    if (blockIdx.x == 0 && threadIdx.x == 0) {
        int cnt = 0;
        for (int i = 0; i < 256; ++i) {
            unsigned lo = xw[i] & 0xFFFFu;
            int e = (int)((lo >> 7) & 0xFF);
            if (e >= 112 && e <= 132) ++cnt;
        }
        *flag = (cnt >= 128) ? 1 : 0;
    }
}

// -- fused prep: wpack | affine | mixbias | dw-transpose | mix-weights f32
struct PtrArgs { const void* p[26]; };
__global__ __launch_bounds__(256) void k_prep(PtrArgs a, bf16* __restrict__ Wqkv,
                                              float* __restrict__ al, float* __restrict__ be,
                                              float* __restrict__ mb, bf16* __restrict__ Wvlt,
                                              float* __restrict__ w1f, float* __restrict__ w2f,
                                              const int* __restrict__ flag)
{
    const int isb = *flag;
    const int tid = threadIdx.x;
    const int role = blockIdx.y;
    if (role == 0) {
        int stride = gridDim.x * 256;
        for (int e = blockIdx.x * 256 + tid; e < 1536 * 384; e += stride) {
            int co = e / 384, k = e % 384;
            const void* src; int lc;
            if (co < 256)      { src = a.p[1]; lc = co; }
            else if (co < 512) { src = a.p[5]; lc = co - 256; }
            else               { src = a.p[9]; lc = co - 512; }
            Wqkv[e] = f2b(ldf(src, (size_t)lc * 384 + k, isb));
        }
    } else if (role == 1) {
        int co = blockIdx.x * 256 + tid;
        if (co < 1536) {
            const void *b_, *s_, *h_; int lc;
            if (co < 256)      { b_ = a.p[2];  s_ = a.p[3];  h_ = a.p[4];  lc = co; }
            else if (co < 512) { b_ = a.p[6];  s_ = a.p[7];  h_ = a.p[8];  lc = co - 256; }
            else               { b_ = a.p[10]; s_ = a.p[11]; h_ = a.p[12]; lc = co - 512; }
            float aa = ldf(s_, lc, isb);
            al[co] = aa;
            be[co] = ldf(b_, lc, isb) * aa + ldf(h_, lc, isb);
        }
    } else if (role == 2) {
        int i = blockIdx.x * 256 + tid;
        if (i < 8 * Nn) {
            int g = i / Nn, p = i % Nn;
            float acc = ldf(a.p[18], g, isb);
            #pragma unroll
            for (int h = 0; h < 8; ++h)
                acc += ldf(a.p[17], g * 8 + h, isb) * ldf(a.p[25], (size_t)h * Nn + p, isb);
            mb[i] = acc;
        }
    } else if (role == 3) {
        int e = blockIdx.x * 256 + tid;   // Wvl [1024][9] -> Wvlt [9][1024]
        if (e < 1024 * 9) {
            int c = e / 9, tap = e % 9;
            Wvlt[tap * 1024 + c] = f2b(ldf(a.p[13], e, isb));
        }
    } else {
        if (blockIdx.x == 0 && tid < 128) {
            if (tid < 64) w1f[tid] = ldf(a.p[17], tid, isb) * 0.17677669529663687f;
            else          w2f[tid - 64] = ldf(a.p[19], tid - 64, isb);
        }
    }
}

// ------------------------------------- convert needed tensors -> bf16
struct ConvArgs { const void* src[10]; unsigned long long dstoff[10]; int n[10]; };
__global__ void k_convb_all(ConvArgs a, char* __restrict__ ws, const int* __restrict__ flag)
{
    int i = blockIdx.y;
    int n = a.n[i];
    const void* s = a.src[i];
    bf16* d = (bf16*)(ws + a.dstoff[i]);
    int isb = *flag;
    int stride = gridDim.x * blockDim.x;
    for (int t = blockIdx.x * blockDim.x + threadIdx.x; t < n; t += stride)
        d[t] = isb ? ((const bf16*)s)[t] : f2b(((const float*)s)[t]);
}

// ------------------- expand mb through idx: abfull[g][n][m] (b-independent)
__global__ __launch_bounds__(256) void k_abfull(
    const float* __restrict__ mb, const int* __restrict__ idxs,
    bf16* __restrict__ abfull)
{
    __shared__ float mbs[8][Nn];
    const int tid = threadIdx.x;
    for (int i = tid; i < 8 * Nn; i += 256) ((float*)mbs)[i] = mb[i];
    __syncthreads();
    const int nstart = blockIdx.x * 2;
    for (int n = nstart; n < nstart + 2; ++n) {
        for (int m = tid; m < Nn; m += 256) {
            int id = idxs[(size_t)n * Nn + m];
            #pragma unroll
            for (int g = 0; g < 8; ++g)
                abfull[((size_t)g * Nn + n) * AST + m] = f2b(mbs[g][id]);
        }
    }
}

// ------------- x transpose + inline convert: [b][384][784] -> [b][784][384]
__global__ __launch_bounds__(256) void k_xt(const void* __restrict__ xr, bf16* __restrict__ xt,
                                            const int* __restrict__ flag)
{
    const int isb = *flag;
    __shared__ bf16 t[32][33];
    int b = blockIdx.z, n0 = blockIdx.x * 32, c0 = blockIdx.y * 32;
    int tid = threadIdx.x;
    for (int i = tid; i < 1024; i += 256) {
        int r = i >> 5, c = i & 31;
        int n = n0 + c;
        t[r][c] = (n < Nn) ? f2b(ldf(xr, ((size_t)b * CIN + c0 + r) * Nn + n, isb)) : f2b(0.f);
    }
    __syncthreads();
    for (int i = tid; i < 1024; i += 256) {
        int r = i >> 5, c = i & 31;
        int n = n0 + r;
        if (n < Nn) xt[((size_t)b * Nn + n) * CIN + c0 + c] = t[c][r];
    }
}

// ----- merged: v transpose (x<25) | v colsum (x==25, y<16); both read vbuf
__global__ __launch_bounds__(256) void k_vt_cs(const bf16* __restrict__ vbuf,
                                               bf16* __restrict__ vt,
                                               float* __restrict__ colsum)
{
    const int b = blockIdx.z;
    const int tid = threadIdx.x;
    if (blockIdx.x < 25) {
        __shared__ bf16 t[32][33];
        int n0 = blockIdx.x * 32, c0 = blockIdx.y * 32;
        for (int i = tid; i < 1024; i += 256) {
            int r = i >> 5, c = i & 31;
            int n = n0 + r;
            t[r][c] = (n < Nn) ? vbuf[((size_t)b * Nn + n) * DHn + c0 + c] : f2b(0.f);
        }
        __syncthreads();
        for (int i = tid; i < 1024; i += 256) {
            int r = i >> 5, c = i & 31;
            int n = n0 + c;   // n < 800 always
            vt[((size_t)b * DHn + c0 + r) * AST + n] = t[c][r];
        }
    } else if (blockIdx.y < 16) {
        __shared__ float red[4][64];
        const int c0 = blockIdx.y * 64;
        const int cl = tid & 63, part = tid >> 6;
        float s = 0.f;
        const int nst = part * 196;
        for (int n = nst; n < nst + 196; ++n)
            s += b2f(vbuf[((size_t)b * Nn + n) * DHn + c0 + cl]);
        red[part][cl] = s;
        __syncthreads();
        if (tid < 64)
            colsum[(size_t)b * DHn + c0 + tid] = red[0][tid] + red[1][tid] + red[2][tid] + red[3][tid];
    }
}

// -------------------- frag-linear staging: 64 rows x 32 k of a K-contig matrix
__device__ __forceinline__ void stage64x32(const bf16* __restrict__ src,
    int row0, int row_lim, int k0, int k_lim, int ld, short* lds, int tid)
{
    int rsub = ((tid >> 6) << 4) | (tid & 15);
    int q    = (tid >> 4) & 3;
    int row = row0 + rsub; row = row < row_lim ? row : row_lim - 1;
    gload16((const short*)src + (size_t)row * ld + k0 + q * 8,
            lds + (size_t)(((rsub >> 4) * 4 + q) * 16 + (rsub & 15)) * 8);
}

// ------------------- generic MFMA core: tile (MI*32) x 128, BK=32, gload_lds
template<int MI>
__device__ __forceinline__ void gemm_core(
    const bf16* __restrict__ A, int lda, int rowsA, int arow0,
    const bf16* __restrict__ B, int ldb, int rowsB, int brow0,
    int K, short* ldsA, short* ldsB, f32x4 (&acc)[MI][4])
{
    const int tid  = threadIdx.x;
    const int lane = tid & 63;
    const int wm   = tid >> 7, wn = (tid >> 6) & 1;
    const short8v* A8 = (const short8v*)ldsA;
    const short8v* B8 = (const short8v*)ldsB;

    for (int k0 = 0; k0 < K; k0 += 32) {
        __syncthreads();
        #pragma unroll
        for (int c = 0; c < MI / 2; ++c)
            stage64x32(A, arow0 + c * 64, rowsA, k0, K, lda, ldsA + c * 2048, tid);
        #pragma unroll
        for (int c = 0; c < 2; ++c)
            stage64x32(B, brow0 + c * 64, rowsB, k0, K, ldb, ldsB + c * 2048, tid);
        __syncthreads();
        short8v a[MI], bb[4];
        #pragma unroll
        for (int i = 0; i < MI; ++i) a[i] = A8[(wm * MI + i) * 64 + lane];
        #pragma unroll
        for (int j = 0; j < 4; ++j) bb[j] = B8[(wn * 4 + j) * 64 + lane];
        #pragma unroll
        for (int i = 0; i < MI; ++i)
            #pragma unroll
            for (int j = 0; j < 4; ++j)
                acc[i][j] = __builtin_amdgcn_mfma_f32_16x16x32_bf16(a[i], bb[j], acc[i][j], 0, 0, 0);
    }
}

#define EPI_COORDS(MI)                                      \
    const int tid  = threadIdx.x;                           \
    const int lane = tid & 63;                              \
    const int wm   = tid >> 7, wn = (tid >> 6) & 1;         \
    const int rq   = lane >> 4, cl = lane & 15; (void)rq;

// --------------------------------------------- q/k/v projection + BN (MFMA)
__global__ __launch_bounds__(256) void k_proj_m(
    const bf16* __restrict__ xt, const bf16* __restrict__ Wqkv,
    const float* __restrict__ al, const float* __restrict__ be,
    bf16* __restrict__ qbuf, bf16* __restrict__ kbuf, bf16* __restrict__ vbuf)
{
    __shared__ short ldsA[4096], ldsB[4096];
    const int n0 = blockIdx.x * 128, co0 = blockIdx.y * 128;
    const int b = blockIdx.z;
    f32x4 acc[4][4] = {};
    gemm_core<4>(xt + (size_t)b * Nn * CIN, CIN, Nn, n0,
                 Wqkv, CIN, 1536, co0, CIN, ldsA, ldsB, acc);
    EPI_COORDS(4)
    #pragma unroll
    for (int i = 0; i < 4; ++i)
        #pragma unroll
        for (int j = 0; j < 4; ++j) {
            int co = co0 + (wn * 4 + j) * 16 + cl;
            float a_ = al[co], bb_ = be[co];
            int nb = n0 + (wm * 4 + i) * 16 + rq * 4;
            #pragma unroll
            for (int r = 0; r < 4; ++r) {
                int n = nb + r;
                if (n >= Nn) continue;
                float y = a_ * acc[i][j][r] + bb_;
                if (co < 256)      qbuf[((size_t)b * Nn + n) * 256 + co]       = f2b(y);
                else if (co < 512) kbuf[((size_t)b * Nn + n) * 256 + (co-256)] = f2b(y);
                else               vbuf[((size_t)b * Nn + n) * DHn + (co-512)] = f2b(y);
            }
        }
}

// ------------- raw per-head logits: qk[h][n][m] -> bf8, K=32 (no mix/bias)
__global__ __launch_bounds__(256) void k_logits_raw(
    const bf16* __restrict__ qbuf, const bf16* __restrict__ kbuf,
    unsigned char* __restrict__ attn, int bi0)
{
    __shared__ short ldsA[4096], ldsB[4096];
    const int n0 = blockIdx.x * 128, m0 = blockIdx.y * 128;
    const int z = blockIdx.z, h = z & 7, bloc = z >> 3, b = bi0 + bloc;
    f32x4 acc[4][4] = {};
    gemm_core<4>(qbuf + (size_t)b * Nn * 256 + h * 32, 256, Nn, n0,
                 kbuf + (size_t)b * Nn * 256 + h * 32, 256, Nn, m0,
                 32, ldsA, ldsB, acc);
    unsigned char* arow = attn + (size_t)(bloc * 8 + h) * Nn * AST;
    EPI_COORDS(4)
    #pragma unroll
    for (int i = 0; i < 4; ++i)
        #pragma unroll
        for (int j = 0; j < 4; ++j) {
            int m = m0 + (wn * 4 + j) * 16 + cl;
            if (m >= Nn) continue;
            int nb = n0 + (wm * 4 + i) * 16 + rq * 4;
            #pragma unroll
            for (int r = 0; r < 4; ++r) {
                int n = nb + r;
                if (n < Nn) arow[(size_t)n * AST + m] = (unsigned char)f2bf8_1(acc[i][j][r]);
            }
        }
}

// --- fused: th1 mix (+abfull) + softmax (no-max) + th2 mix (NO b2) -> bf8 P2
// mix weights read from f32 global arrays (uniform idx -> SGPR), packed FMA
__global__ __launch_bounds__(256) void k_softmax_mix(
    const unsigned char* __restrict__ attn_all, unsigned char* __restrict__ p2_all,
    const bf16* __restrict__ abfull,
    const float* __restrict__ w1f, const float* __restrict__ w2f)
{
    const int n = blockIdx.x, bloc = blockIdx.y;
    const int tid = threadIdx.x;
    const unsigned char* base = attn_all + (size_t)bloc * 8 * Nn * AST;
    unsigned char* p2b = p2_all + (size_t)bloc * 8 * Nn * AST;
    __shared__ float lis[8], wred[4][8];

    const bool live = tid < 196;
    const int m0 = (live ? tid : 195) * 4;

    f32x2 raw2[8][2];
    #pragma unroll
    for (int h = 0; h < 8; ++h) {
        unsigned u = *(const unsigned*)(base + ((size_t)h * Nn + n) * AST + m0);
        unpack4_bf8_pk(u, raw2[h][0], raw2[h][1]);
    }

    f32x2 out2[8][2];
    #pragma unroll
    for (int g = 0; g < 8; ++g) {
        short4v bv = *(const short4v*)(abfull + ((size_t)g * Nn + n) * AST + m0);
        f32x2 a0 = {su2f(bv[0]), su2f(bv[1])};
        f32x2 a1 = {su2f(bv[2]), su2f(bv[3])};
        #pragma unroll
        for (int h = 0; h < 8; ++h) {
            float w = w1f[g * 8 + h];
            f32x2 wv = {w, w};
            a0 += raw2[h][0] * wv;
            a1 += raw2[h][1] * wv;
        }
        f32x2 e0, e1;
        e0[0] = __expf(fminf(a0[0], 60.f));
        e0[1] = __expf(fminf(a0[1], 60.f));
        e1[0] = __expf(fminf(a1[0], 60.f));
        e1[1] = __expf(fminf(a1[1], 60.f));
        out2[g][0] = e0;
        out2[g][1] = e1;
        float s = live ? (e0[0] + e0[1]) + (e1[0] + e1[1]) : 0.f;
        #pragma unroll
        for (int sh = 32; sh > 0; sh >>= 1) s += __shfl_xor(s, sh, 64);
        if ((tid & 63) == 0) wred[tid >> 6][g] = s;
    }
    __syncthreads();
    if (tid < 8)
        lis[tid] = 1.f / (wred[0][tid] + wred[1][tid] + wred[2][tid] + wred[3][tid]);
    __syncthreads();

    #pragma unroll
    for (int h = 0; h < 8; ++h) {
        float lh = lis[h];
        f32x2 lv = {lh, lh};
        out2[h][0] *= lv;
        out2[h][1] *= lv;
    }
    if (live) {
        #pragma unroll
        for (int g = 0; g < 8; ++g) {
            f32x2 acc0 = {0.f, 0.f};
            f32x2 acc1 = {0.f, 0.f};
            #pragma unroll
            for (int h = 0; h < 8; ++h) {
                float w = w2f[g * 8 + h];
                f32x2 wv = {w, w};
                acc0 += out2[h][0] * wv;
                acc1 += out2[h][1] * wv;
            }
            unsigned u = pack4_bf8(acc0[0], acc0[1], acc1[0], acc1[1]);
            *(unsigned*)(p2b + ((size_t)g * Nn + n) * AST + m0) = u;
        }
    }
}

// ------- PV: obuf[b][n][c] = P2mix(bf8) . v  + b2[g]*colsum_v  (MFMA bf16)
__global__ __launch_bounds__(256) void k_pv_m(
    const unsigned char* __restrict__ p2, const bf16* __restrict__ vt,
    const bf16* __restrict__ b2v, const float* __restrict__ colsum,
    bf16* __restrict__ obuf, int bi0)
{
    __shared__ short ldsA[2048], ldsB[4096];
    const int tid = threadIdx.x;
    const int n0 = blockIdx.x * 64;
    const int z = blockIdx.z, g = z & 7, bloc = z >> 3, b = bi0 + bloc;
    const unsigned char* Ap = p2 + (size_t)(bloc * 8 + g) * Nn * AST;
    const bf16* Bv = vt + ((size_t)b * DHn + g * 128) * AST;
    const int lane = tid & 63;
    const int wm = tid >> 7, wn = (tid >> 6) & 1;
    const int rsub = ((tid >> 6) << 4) | (tid & 15);
    const int q = (tid >> 4) & 3;
    const short8v* A8 = (const short8v*)ldsA;
    const short8v* B8 = (const short8v*)ldsB;
    f32x4 acc[2][4] = {};

    for (int k0 = 0; k0 < AST; k0 += 32) {
        __syncthreads();
        {   // A stage: load 8 bf8 bytes, HW-decode -> bf16 frag slot
            int row = n0 + rsub; row = row < Nn ? row : Nn - 1;
            const unsigned char* src = Ap + (size_t)row * AST + k0 + q * 8;
            unsigned lo = *(const unsigned*)src;
            unsigned hi = *(const unsigned*)(src + 4);
            float d0[4], d1[4];
            unpack4_bf8(lo, d0);
            unpack4_bf8(hi, d1);
            short8v o;
            #pragma unroll
            for (int j = 0; j < 4; ++j) { o[j] = f2s(d0[j]); o[4 + j] = f2s(d1[j]); }
            ((short8v*)ldsA)[((rsub >> 4) * 4 + q) * 16 + (rsub & 15)] = o;
        }
        stage64x32(Bv, 0,  128, k0, AST, AST, ldsB, tid);
        stage64x32(Bv, 64, 128, k0, AST, AST, ldsB + 2048, tid);
        __syncthreads();
        short8v a[2], bb[4];
        #pragma unroll
        for (int i = 0; i < 2; ++i) a[i] = A8[(wm * 2 + i) * 64 + lane];
        #pragma unroll
        for (int j = 0; j < 4; ++j) bb[j] = B8[(wn * 4 + j) * 64 + lane];
        #pragma unroll
        for (int i = 0; i < 2; ++i)
            #pragma unroll
            for (int j = 0; j < 4; ++j)
                acc[i][j] = __builtin_amdgcn_mfma_f32_16x16x32_bf16(a[i], bb[j], acc[i][j], 0, 0, 0);
    }

    bf16* ob = obuf + (size_t)b * Nn * DHn + g * 128;
    const float b2g = b2f(b2v[g]);
    const int rq = lane >> 4, cl = lane & 15;
    #pragma unroll
    for (int i = 0; i < 2; ++i)
        #pragma unroll
        for (int j = 0; j < 4; ++j) {
            int d = (wn * 4 + j) * 16 + cl;
            float cs = b2g * colsum[(size_t)b * DHn + g * 128 + d];
            int nb = n0 + (wm * 2 + i) * 16 + rq * 4;
            #pragma unroll
            for (int r = 0; r < 4; ++r) {
                int n = nb + r;
                if (n < Nn) ob[(size_t)n * DHn + d] = f2b(acc[i][j][r] + cs);
            }
        }
}

// ---- depthwise conv+BN, ADDS into obuf (o += vl), fully vectorized weights
__global__ __launch_bounds__(256) void k_dwconv_add(
    const bf16* __restrict__ vbuf, const bf16* __restrict__ Wvlt,
    const bf16* __restrict__ bvl, const bf16* __restrict__ vls, const bf16* __restrict__ vlb,
    bf16* __restrict__ obuf)
{
    const int t = threadIdx.x;
    const int n = blockIdx.y * 2 + (t >> 7);
    const int bi = blockIdx.z;
    const int c0 = (t & 127) * 8;
    const int h = n / RESn, w = n % RESn;
    float acc[8] = {};
    #pragma unroll
    for (int dh = -1; dh <= 1; ++dh)
        #pragma unroll
        for (int dw = -1; dw <= 1; ++dw) {
            int hh = h + dh, ww = w + dw;
            if (hh < 0 || hh >= RESn || ww < 0 || ww >= RESn) continue;
            int widx = (dh + 1) * 3 + (dw + 1);
            short8v wv = *(const short8v*)&Wvlt[widx * 1024 + c0];
            short8v v  = *(const short8v*)&vbuf[((size_t)bi * Nn + hh * RESn + ww) * DHn + c0];
            #pragma unroll
            for (int u = 0; u < 8; ++u)
                acc[u] += su2f(wv[u]) * su2f(v[u]);
        }
    short8v bv = *(const short8v*)&bvl[c0];
    short8v sv = *(const short8v*)&vls[c0];
    short8v hv = *(const short8v*)&vlb[c0];
    size_t off = ((size_t)bi * Nn + n) * DHn + c0;
    short8v ov = *(short8v*)&obuf[off];
    short8v res;
    #pragma unroll
    for (int u = 0; u < 8; ++u) {
        float vl = su2f(sv[u]) * (acc[u] + su2f(bv[u])) + su2f(hv[u]);
        res[u] = f2s(su2f(ov[u]) + vl);
    }
    *(short8v*)&obuf[off] = res;
}

// --------------------------------------------- output projection + BN (MFMA)
__global__ __launch_bounds__(256) void k_outproj_m(
    const bf16* __restrict__ Wp, const bf16* __restrict__ obuf,
    const bf16* __restrict__ bp, const bf16* __restrict__ ps, const bf16* __restrict__ pb,
    void* __restrict__ outv, const int* __restrict__ flag)
{
    __shared__ short ldsA[2048], ldsB[4096];
    const int n0 = blockIdx.x * 128, oc0 = blockIdx.y * 64;
    const int b = blockIdx.z;
    f32x4 acc[2][4] = {};
    gemm_core<2>(Wp, DHn, 384, oc0,
                 obuf + (size_t)b * Nn * DHn, DHn, Nn, n0,
                 DHn, ldsA, ldsB, acc);
    const int isb = *flag;
    EPI_COORDS(2)
    #pragma unroll
    for (int i = 0; i < 2; ++i)
        #pragma unroll
        for (int j = 0; j < 4; ++j) {
            int n = n0 + (wn * 4 + j) * 16 + cl;
            if (n >= Nn) continue;
            int ocb = oc0 + (wm * 2 + i) * 16 + rq * 4;
            #pragma unroll
            for (int r = 0; r < 4; ++r) {
                int oc = ocb + r;
                float a_ = b2f(ps[oc]);
                float be_ = b2f(bp[oc]) * a_ + b2f(pb[oc]);
                float y = a_ * acc[i][j][r] + be_;
                size_t idx = ((size_t)b * CIN + oc) * Nn + n;
                if (isb) ((bf16*)outv)[idx] = f2b(y);
                else     ((float*)outv)[idx] = y;
            }
        }
}

extern "C" void kernel_launch(void* const* d_in, const int* in_sizes, int n_in,
                              void* d_out, int out_size, void* d_ws, size_t ws_size,
                              hipStream_t stream)
{
    char* ws = (char*)d_ws;
    auto align256 = [](size_t v) { return (v + 255) & ~(size_t)255; };

    size_t off = 0;
    size_t off_flag = off;            off = align256(off + 4);
    size_t p_off[26];
    for (int i = 0; i < 26; ++i) { p_off[i] = off; off = align256(off + (size_t)in_sizes[i] * 2); }
    size_t off_mb   = off; off = align256(off + (size_t)8 * Nn * 4);
    size_t off_ab   = off; off = align256(off + (size_t)8 * Nn * AST * 2);
    size_t off_q    = off; off = align256(off + (size_t)Bn * Nn * 256 * 2);
    size_t off_k    = off; off = align256(off + (size_t)Bn * Nn * 256 * 2);
    size_t off_v    = off; off = align256(off + (size_t)Bn * Nn * DHn * 2);
    size_t off_vt   = off; off = align256(off + (size_t)Bn * DHn * AST * 2);
    size_t off_o    = off; off = align256(off + (size_t)Bn * Nn * DHn * 2);
    size_t off_xt   = off; off = align256(off + (size_t)Bn * Nn * CIN * 2);
    size_t off_wqkv = off; off = align256(off + (size_t)1536 * CIN * 2);
    size_t off_al   = off; off = align256(off + (size_t)1536 * 4);
    size_t off_be   = off; off = align256(off + (size_t)1536 * 4);
    size_t off_wvlt = off; off = align256(off + (size_t)9 * 1024 * 2);
    size_t off_cs   = off; off = align256(off + (size_t)Bn * DHn * 4);
    size_t off_w1f  = off; off = align256(off + 64 * 4);
    size_t off_w2f  = off; off = align256(off + 64 * 4);
    size_t base = off;

    const size_t attn_per_b = (size_t)8 * Nn * AST;      // S bf8
    const size_t p2_per_b   = (size_t)8 * Nn * AST;      // P2 bf8
    int GB = 0;
    const int cand[4] = {8, 4, 2, 1};
    for (int ci = 0; ci < 4; ++ci) {
        if (base + (size_t)cand[ci] * (attn_per_b + p2_per_b) + 512 <= ws_size) { GB = cand[ci]; break; }
    }
    if (!GB) return; // ws too small -> zeros out (diagnostic absmax ~17.4)

    size_t off_attn = base;
    size_t off_p2   = align256(off_attn + (size_t)GB * attn_per_b);

    int*  flag = (int*)(ws + off_flag);
    bf16* Pb[26];
    for (int i = 0; i < 26; ++i) Pb[i] = (bf16*)(ws + p_off[i]);
    float* mb    = (float*)(ws + off_mb);
    bf16* abfull = (bf16*)(ws + off_ab);
    bf16* qbuf  = (bf16*)(ws + off_q);
    bf16* kbuf  = (bf16*)(ws + off_k);
    bf16* vbuf  = (bf16*)(ws + off_v);
    bf16* vt    = (bf16*)(ws + off_vt);
    bf16* obuf  = (bf16*)(ws + off_o);
    bf16* xt    = (bf16*)(ws + off_xt);
    bf16* wqkv  = (bf16*)(ws + off_wqkv);
    float* alf  = (float*)(ws + off_al);
    float* bef  = (float*)(ws + off_be);
    bf16* wvlt  = (bf16*)(ws + off_wvlt);
    float* csum = (float*)(ws + off_cs);
    float* w1f  = (float*)(ws + off_w1f);
    float* w2f  = (float*)(ws + off_w2f);
    unsigned char* attn = (unsigned char*)(ws + off_attn);
    unsigned char* p2b  = (unsigned char*)(ws + off_p2);
    const int* idxs = (const int*)d_in[26];

    k_detect<<<1, 64, 0, stream>>>((const unsigned*)d_in[0], flag);

    PtrArgs pa;
    for (int i = 0; i < 26; ++i) pa.p[i] = d_in[i];
    k_prep<<<dim3(288, 5), 256, 0, stream>>>(pa, wqkv, alf, bef, mb, wvlt, w1f, w2f, flag);

    const int cidx[10] = {14, 15, 16, 17, 19, 20, 21, 22, 23, 24};
    ConvArgs ca;
    for (int i = 0; i < 10; ++i) {
        ca.src[i] = d_in[cidx[i]];
        ca.dstoff[i] = p_off[cidx[i]];
        ca.n[i] = in_sizes[cidx[i]];
    }
    k_convb_all<<<dim3(64, 10), 256, 0, stream>>>(ca, ws, flag);

    bf16 *bvl = Pb[14], *vls = Pb[15], *vlb = Pb[16],
         *b2v = Pb[20],
         *Wp = Pb[21], *bp = Pb[22], *ps = Pb[23], *pb = Pb[24];

    k_xt<<<dim3(25, 12, 8), 256, 0, stream>>>(d_in[0], xt, flag);
    k_abfull<<<dim3(392), 256, 0, stream>>>(mb, idxs, abfull);

    k_proj_m<<<dim3(7, 12, 8), 256, 0, stream>>>(xt, wqkv, alf, bef, qbuf, kbuf, vbuf);
    k_vt_cs<<<dim3(26, 32, 8), 256, 0, stream>>>(vbuf, vt, csum);

    for (int bi0 = 0; bi0 < Bn; bi0 += GB) {
        k_logits_raw<<<dim3(7, 7, GB * 8), 256, 0, stream>>>(qbuf, kbuf, attn, bi0);
        k_softmax_mix<<<dim3(Nn, GB), 256, 0, stream>>>(attn, p2b, abfull, w1f, w2f);
        k_pv_m<<<dim3(13, 1, GB * 8), 256, 0, stream>>>(p2b, vt, b2v, csum, obuf, bi0);
    }

    k_dwconv_add<<<dim3(1, Nn / 2, 8), 256, 0, stream>>>(vbuf, wvlt, bvl, vls, vlb, obuf);
    k_outproj_m<<<dim3(7, 6, 8), 256, 0, stream>>>(Wp, obuf, bp, ps, pb, d_out, flag);
}

// Round 18
// 213.849 us; speedup vs baseline: 1.1355x; 1.0484x over previous
//
#include <hip/hip_runtime.h>
#include <hip/hip_bf16.h>
#include <hip/hip_fp16.h>

typedef __hip_bfloat16 bf16;
typedef __attribute__((ext_vector_type(8))) short short8v;
typedef __attribute__((ext_vector_type(4))) short short4v;
typedef __attribute__((ext_vector_type(4))) float f32x4;
typedef __attribute__((ext_vector_type(2))) float f32x2;

__device__ __forceinline__ float b2f(bf16 v){ return __bfloat162float(v); }
__device__ __forceinline__ bf16  f2b(float v){ return __float2bfloat16(v); }
__device__ __forceinline__ float su2f(short s){
    unsigned short us = (unsigned short)s;
    return __bfloat162float(*reinterpret_cast<bf16*>(&us));
}
__device__ __forceinline__ short f2s(float v){
    bf16 b = __float2bfloat16(v);
    return *reinterpret_cast<short*>(&b);
}
__device__ __forceinline__ float ldf(const void* t, size_t i, int isb){
    return isb ? b2f(((const bf16*)t)[i]) : ((const float*)t)[i];
}

#if __has_builtin(__builtin_amdgcn_exp2f)
#define EXP2F(x) __builtin_amdgcn_exp2f(x)
#else
#define EXP2F(x) exp2f(x)
#endif

// ---- bf8 (e5m2) codec: HW cvt_pk if available, else f16-path software RNE ----
__device__ __forceinline__ unsigned f2bf8_sw(float f){
    unsigned short h = __half_as_ushort(__float2half(f));
    unsigned lsb = (h >> 8) & 1u, rb = (h >> 7) & 1u, st = (h & 0x7Fu) ? 1u : 0u;
    return ((unsigned)(h >> 8) + (rb & (st | lsb))) & 0xFFu;
}
__device__ __forceinline__ float bf82f_sw(unsigned b){
    return __half2float(__ushort_as_half((unsigned short)(b << 8)));
}
__device__ __forceinline__ unsigned pack4_bf8(float a0, float a1, float a2, float a3){
#if __has_builtin(__builtin_amdgcn_cvt_pk_bf8_f32)
    int u = __builtin_amdgcn_cvt_pk_bf8_f32(a0, a1, 0, false);
    u = __builtin_amdgcn_cvt_pk_bf8_f32(a2, a3, u, true);
    return (unsigned)u;
#else
    return f2bf8_sw(a0) | (f2bf8_sw(a1) << 8) | (f2bf8_sw(a2) << 16) | (f2bf8_sw(a3) << 24);
#endif
}
__device__ __forceinline__ unsigned f2bf8_1(float f){
#if __has_builtin(__builtin_amdgcn_cvt_pk_bf8_f32)
    return (unsigned)__builtin_amdgcn_cvt_pk_bf8_f32(f, f, 0, false) & 0xFFu;
#else
    return f2bf8_sw(f);
#endif
}
__device__ __forceinline__ void unpack4_bf8(unsigned u, float* o){
#if __has_builtin(__builtin_amdgcn_cvt_pk_f32_bf8)
    f32x2 lo = __builtin_amdgcn_cvt_pk_f32_bf8((int)u, false);
    f32x2 hi = __builtin_amdgcn_cvt_pk_f32_bf8((int)u, true);
    o[0] = lo[0]; o[1] = lo[1]; o[2] = hi[0]; o[3] = hi[1];
#else
    o[0] = bf82f_sw(u & 0xFFu);         o[1] = bf82f_sw((u >> 8) & 0xFFu);
    o[2] = bf82f_sw((u >> 16) & 0xFFu); o[3] = bf82f_sw((u >> 24) & 0xFFu);
#endif
}
__device__ __forceinline__ void unpack4_bf8_pk(unsigned u, f32x2& lo, f32x2& hi){
#if __has_builtin(__builtin_amdgcn_cvt_pk_f32_bf8)
    lo = __builtin_amdgcn_cvt_pk_f32_bf8((int)u, false);
    hi = __builtin_amdgcn_cvt_pk_f32_bf8((int)u, true);
#else
    lo = f32x2{bf82f_sw(u & 0xFFu), bf82f_sw((u >> 8) & 0xFFu)};
    hi = f32x2{bf82f_sw((u >> 16) & 0xFFu), bf82f_sw((u >> 24) & 0xFFu)};
#endif
}

constexpr int Bn = 8, CIN = 384, RESn = 28, Nn = 784, DHn = 1024;
constexpr int AST = 800;   // padded attn/vt K-stride (25*32)
constexpr float LOG2E = 1.4426950408889634f;

// ---------------------------------------------------- async global->LDS 16B
__device__ __forceinline__ void gload16(const void* g, void* l)
{
    __builtin_amdgcn_global_load_lds(
        (const __attribute__((address_space(1))) void*)g,
        (__attribute__((address_space(3))) void*)l, 16, 0, 0);
}

// -------------------------------------------------- dtype detector (1 thread)
__global__ void k_detect(const unsigned* __restrict__ xw, int* __restrict__ flag)
{
    if (blockIdx.x == 0 && threadIdx.x == 0) {
        int cnt = 0;
        for (int i = 0; i < 256; ++i) {
            unsigned lo = xw[i] & 0xFFFFu;
            int e = (int)((lo >> 7) & 0xFF);
            if (e >= 112 && e <= 132) ++cnt;
        }
        *flag = (cnt >= 128) ? 1 : 0;
    }
}

// -- fused prep: wpack|affine|mixbias|dw-transpose|mix-weights|8x bf16 convs
struct PtrArgs { const void* p[26]; };
struct ConvArgs { const void* src[8]; unsigned long long dstoff[8]; int n[8]; };
__global__ __launch_bounds__(256) void k_prep(PtrArgs a, ConvArgs ca, char* __restrict__ ws,
                                              bf16* __restrict__ Wqkv,
                                              float* __restrict__ al, float* __restrict__ be,
                                              float* __restrict__ mb, bf16* __restrict__ Wvlt,
                                              float* __restrict__ w1f, float* __restrict__ w2f,
                                              const int* __restrict__ flag)
{
    const int isb = *flag;
    const int tid = threadIdx.x;
    const int role = blockIdx.y;
    if (role == 0) {
        int stride = gridDim.x * 256;
        for (int e = blockIdx.x * 256 + tid; e < 1536 * 384; e += stride) {
            int co = e / 384, k = e % 384;
            const void* src; int lc;
            if (co < 256)      { src = a.p[1]; lc = co; }
            else if (co < 512) { src = a.p[5]; lc = co - 256; }
            else               { src = a.p[9]; lc = co - 512; }
            Wqkv[e] = f2b(ldf(src, (size_t)lc * 384 + k, isb));
        }
    } else if (role == 1) {
        int co = blockIdx.x * 256 + tid;
        if (co < 1536) {
            const void *b_, *s_, *h_; int lc;
            if (co < 256)      { b_ = a.p[2];  s_ = a.p[3];  h_ = a.p[4];  lc = co; }
            else if (co < 512) { b_ = a.p[6];  s_ = a.p[7];  h_ = a.p[8];  lc = co - 256; }
            else               { b_ = a.p[10]; s_ = a.p[11]; h_ = a.p[12]; lc = co - 512; }
            float aa = ldf(s_, lc, isb);
            al[co] = aa;
            be[co] = ldf(b_, lc, isb) * aa + ldf(h_, lc, isb);
        }
    } else if (role == 2) {
        int i = blockIdx.x * 256 + tid;
        if (i < 8 * Nn) {
            int g = i / Nn, p = i % Nn;
            float acc = ldf(a.p[18], g, isb);
            #pragma unroll
            for (int h = 0; h < 8; ++h)
                acc += ldf(a.p[17], g * 8 + h, isb) * ldf(a.p[25], (size_t)h * Nn + p, isb);
            mb[i] = acc;
        }
    } else if (role == 3) {
        int e = blockIdx.x * 256 + tid;   // Wvl [1024][9] -> Wvlt [9][1024]
        if (e < 1024 * 9) {
            int c = e / 9, tap = e % 9;
            Wvlt[tap * 1024 + c] = f2b(ldf(a.p[13], e, isb));
        }
    } else if (role == 4) {
        if (blockIdx.x == 0 && tid < 128) {
            if (tid < 64) w1f[tid] = ldf(a.p[17], tid, isb) * 0.17677669529663687f * LOG2E;
            else          w2f[tid - 64] = ldf(a.p[19], tid - 64, isb);
        }
    } else {
        int r = role - 5;
        int n = ca.n[r];
        const void* s = ca.src[r];
        bf16* d = (bf16*)(ws + ca.dstoff[r]);
        int stride = gridDim.x * 256;
        for (int t = blockIdx.x * 256 + tid; t < n; t += stride)
            d[t] = isb ? ((const bf16*)s)[t] : f2b(((const float*)s)[t]);
    }
}

// ------- merged: x transpose (z<8) | abfull expand scaled by log2e (z==8)
__global__ __launch_bounds__(256) void k_xt_ab(
    const void* __restrict__ xr, bf16* __restrict__ xt,
    const float* __restrict__ mb, const int* __restrict__ idxs,
    bf16* __restrict__ abfull, const int* __restrict__ flag)
{
    const int tid = threadIdx.x;
    if (blockIdx.z < 8) {
        const int isb = *flag;
        __shared__ bf16 t[32][33];
        int b = blockIdx.z, n0 = blockIdx.x * 32, c0 = blockIdx.y * 32;
        for (int i = tid; i < 1024; i += 256) {
            int r = i >> 5, c = i & 31;
            int n = n0 + c;
            t[r][c] = (n < Nn) ? f2b(ldf(xr, ((size_t)b * CIN + c0 + r) * Nn + n, isb)) : f2b(0.f);
        }
        __syncthreads();
        for (int i = tid; i < 1024; i += 256) {
            int r = i >> 5, c = i & 31;
            int n = n0 + r;
            if (n < Nn) xt[((size_t)b * Nn + n) * CIN + c0 + c] = t[c][r];
        }
    } else {
        const int slot = blockIdx.y * 25 + blockIdx.x;   // 0..299
        for (int n = slot * 3; n < slot * 3 + 3 && n < Nn; ++n) {
            for (int m = tid; m < Nn; m += 256) {
                int id = idxs[(size_t)n * Nn + m];
                #pragma unroll
                for (int g = 0; g < 8; ++g)
                    abfull[((size_t)g * Nn + n) * AST + m] = f2b(mb[g * Nn + id] * LOG2E);
            }
        }
    }
}

// ----- merged: v transpose (x<25) | v colsum (x==25, y<16); both read vbuf
__global__ __launch_bounds__(256) void k_vt_cs(const bf16* __restrict__ vbuf,
                                               bf16* __restrict__ vt,
                                               float* __restrict__ colsum)
{
    const int b = blockIdx.z;
    const int tid = threadIdx.x;
    if (blockIdx.x < 25) {
        __shared__ bf16 t[32][33];
        int n0 = blockIdx.x * 32, c0 = blockIdx.y * 32;
        for (int i = tid; i < 1024; i += 256) {
            int r = i >> 5, c = i & 31;
            int n = n0 + r;
            t[r][c] = (n < Nn) ? vbuf[((size_t)b * Nn + n) * DHn + c0 + c] : f2b(0.f);
        }
        __syncthreads();
        for (int i = tid; i < 1024; i += 256) {
            int r = i >> 5, c = i & 31;
            int n = n0 + c;   // n < 800 always
            vt[((size_t)b * DHn + c0 + r) * AST + n] = t[c][r];
        }
    } else if (blockIdx.y < 16) {
        __shared__ float red[4][64];
        const int c0 = blockIdx.y * 64;
        const int cl = tid & 63, part = tid >> 6;
        float s = 0.f;
        const int nst = part * 196;
        for (int n = nst; n < nst + 196; ++n)
            s += b2f(vbuf[((size_t)b * Nn + n) * DHn + c0 + cl]);
        red[part][cl] = s;
        __syncthreads();
        if (tid < 64)
            colsum[(size_t)b * DHn + c0 + tid] = red[0][tid] + red[1][tid] + red[2][tid] + red[3][tid];
    }
}

// -------------------- frag-linear staging: 64 rows x 32 k of a K-contig matrix
__device__ __forceinline__ void stage64x32(const bf16* __restrict__ src,
    int row0, int row_lim, int k0, int k_lim, int ld, short* lds, int tid)
{
    int rsub = ((tid >> 6) << 4) | (tid & 15);
    int q    = (tid >> 4) & 3;
    int row = row0 + rsub; row = row < row_lim ? row : row_lim - 1;
    gload16((const short*)src + (size_t)row * ld + k0 + q * 8,
            lds + (size_t)(((rsub >> 4) * 4 + q) * 16 + (rsub & 15)) * 8);
}

// ------------------- generic MFMA core: tile (MI*32) x 128, BK=32, gload_lds
template<int MI>
__device__ __forceinline__ void gemm_core(
    const bf16* __restrict__ A, int lda, int rowsA, int arow0,
    const bf16* __restrict__ B, int ldb, int rowsB, int brow0,
    int K, short* ldsA, short* ldsB, f32x4 (&acc)[MI][4])
{
    const int tid  = threadIdx.x;
    const int lane = tid & 63;
    const int wm   = tid >> 7, wn = (tid >> 6) & 1;
    const short8v* A8 = (const short8v*)ldsA;
    const short8v* B8 = (const short8v*)ldsB;

    for (int k0 = 0; k0 < K; k0 += 32) {
        __syncthreads();
        #pragma unroll
        for (int c = 0; c < MI / 2; ++c)
            stage64x32(A, arow0 + c * 64, rowsA, k0, K, lda, ldsA + c * 2048, tid);
        #pragma unroll
        for (int c = 0; c < 2; ++c)
            stage64x32(B, brow0 + c * 64, rowsB, k0, K, ldb, ldsB + c * 2048, tid);
        __syncthreads();
        short8v a[MI], bb[4];
        #pragma unroll
        for (int i = 0; i < MI; ++i) a[i] = A8[(wm * MI + i) * 64 + lane];
        #pragma unroll
        for (int j = 0; j < 4; ++j) bb[j] = B8[(wn * 4 + j) * 64 + lane];
        #pragma unroll
        for (int i = 0; i < MI; ++i)
            #pragma unroll
            for (int j = 0; j < 4; ++j)
                acc[i][j] = __builtin_amdgcn_mfma_f32_16x16x32_bf16(a[i], bb[j], acc[i][j], 0, 0, 0);
    }
}

#define EPI_COORDS(MI)                                      \
    const int tid  = threadIdx.x;                           \
    const int lane = tid & 63;                              \
    const int wm   = tid >> 7, wn = (tid >> 6) & 1;         \
    const int rq   = lane >> 4, cl = lane & 15; (void)rq;

// --------------------------------------------- q/k/v projection + BN (MFMA)
__global__ __launch_bounds__(256) void k_proj_m(
    const bf16* __restrict__ xt, const bf16* __restrict__ Wqkv,
    const float* __restrict__ al, const float* __restrict__ be,
    bf16* __restrict__ qbuf, bf16* __restrict__ kbuf, bf16* __restrict__ vbuf)
{
    __shared__ short ldsA[4096], ldsB[4096];
    const int n0 = blockIdx.x * 128, co0 = blockIdx.y * 128;
    const int b = blockIdx.z;
    f32x4 acc[4][4] = {};
    gemm_core<4>(xt + (size_t)b * Nn * CIN, CIN, Nn, n0,
                 Wqkv, CIN, 1536, co0, CIN, ldsA, ldsB, acc);
    EPI_COORDS(4)
    #pragma unroll
    for (int i = 0; i < 4; ++i)
        #pragma unroll
        for (int j = 0; j < 4; ++j) {
            int co = co0 + (wn * 4 + j) * 16 + cl;
            float a_ = al[co], bb_ = be[co];
            int nb = n0 + (wm * 4 + i) * 16 + rq * 4;
            #pragma unroll
            for (int r = 0; r < 4; ++r) {
                int n = nb + r;
                if (n >= Nn) continue;
                float y = a_ * acc[i][j][r] + bb_;
                if (co < 256)      qbuf[((size_t)b * Nn + n) * 256 + co]       = f2b(y);
                else if (co < 512) kbuf[((size_t)b * Nn + n) * 256 + (co-256)] = f2b(y);
                else               vbuf[((size_t)b * Nn + n) * DHn + (co-512)] = f2b(y);
            }
        }
}

// ------------- raw per-head logits: qk[h][n][m] -> bf8, K=32 (no mix/bias)
__global__ __launch_bounds__(256) void k_logits_raw(
    const bf16* __restrict__ qbuf, const bf16* __restrict__ kbuf,
    unsigned char* __restrict__ attn, int bi0)
{
    __shared__ short ldsA[4096], ldsB[4096];
    const int n0 = blockIdx.x * 128, m0 = blockIdx.y * 128;
    const int z = blockIdx.z, h = z & 7, bloc = z >> 3, b = bi0 + bloc;
    f32x4 acc[4][4] = {};
    gemm_core<4>(qbuf + (size_t)b * Nn * 256 + h * 32, 256, Nn, n0,
                 kbuf + (size_t)b * Nn * 256 + h * 32, 256, Nn, m0,
                 32, ldsA, ldsB, acc);
    unsigned char* arow = attn + (size_t)(bloc * 8 + h) * Nn * AST;
    EPI_COORDS(4)
    #pragma unroll
    for (int i = 0; i < 4; ++i)
        #pragma unroll
        for (int j = 0; j < 4; ++j) {
            int m = m0 + (wn * 4 + j) * 16 + cl;
            if (m >= Nn) continue;
            int nb = n0 + (wm * 4 + i) * 16 + rq * 4;
            #pragma unroll
            for (int r = 0; r < 4; ++r) {
                int n = nb + r;
                if (n < Nn) arow[(size_t)n * AST + m] = (unsigned char)f2bf8_1(acc[i][j][r]);
            }
        }
}

// --- fused: th1 mix (+abfull, log2 domain) + softmax(exp2) + th2 mix -> bf8 P2
__global__ __launch_bounds__(256) void k_softmax_mix(
    const unsigned char* __restrict__ attn_all, unsigned char* __restrict__ p2_all,
    const bf16* __restrict__ abfull,
    const float* __restrict__ w1f, const float* __restrict__ w2f)
{
    const int n = blockIdx.x, bloc = blockIdx.y;
    const int tid = threadIdx.x;
    const unsigned char* base = attn_all + (size_t)bloc * 8 * Nn * AST;
    unsigned char* p2b = p2_all + (size_t)bloc * 8 * Nn * AST;
    __shared__ float lis[8], wred[4][8];

    const bool live = tid < 196;
    const int m0 = (live ? tid : 195) * 4;

    f32x2 raw2[8][2];
    #pragma unroll
    for (int h = 0; h < 8; ++h) {
        unsigned u = *(const unsigned*)(base + ((size_t)h * Nn + n) * AST + m0);
        unpack4_bf8_pk(u, raw2[h][0], raw2[h][1]);
    }

    f32x2 out2[8][2];
    #pragma unroll
    for (int g = 0; g < 8; ++g) {
        short4v bv = *(const short4v*)(abfull + ((size_t)g * Nn + n) * AST + m0);
        f32x2 a0 = {su2f(bv[0]), su2f(bv[1])};
        f32x2 a1 = {su2f(bv[2]), su2f(bv[3])};
        #pragma unroll
        for (int h = 0; h < 8; ++h) {
            float w = w1f[g * 8 + h];
            f32x2 wv = {w, w};
            a0 += raw2[h][0] * wv;
            a1 += raw2[h][1] * wv;
        }
        f32x2 e0, e1;
        e0[0] = EXP2F(fminf(a0[0], 86.f));
        e0[1] = EXP2F(fminf(a0[1], 86.f));
        e1[0] = EXP2F(fminf(a1[0], 86.f));
        e1[1] = EXP2F(fminf(a1[1], 86.f));
        out2[g][0] = e0;
        out2[g][1] = e1;
        float s = live ? (e0[0] + e0[1]) + (e1[0] + e1[1]) : 0.f;
        #pragma unroll
        for (int sh = 32; sh > 0; sh >>= 1) s += __shfl_xor(s, sh, 64);
        if ((tid & 63) == 0) wred[tid >> 6][g] = s;
    }
    __syncthreads();
    if (tid < 8)
        lis[tid] = 1.f / (wred[0][tid] + wred[1][tid] + wred[2][tid] + wred[3][tid]);
    __syncthreads();

    #pragma unroll
    for (int h = 0; h < 8; ++h) {
        float lh = lis[h];
        f32x2 lv = {lh, lh};
        out2[h][0] *= lv;
        out2[h][1] *= lv;
    }
    if (live) {
        #pragma unroll
        for (int g = 0; g < 8; ++g) {
            f32x2 acc0 = {0.f, 0.f};
            f32x2 acc1 = {0.f, 0.f};
            #pragma unroll
            for (int h = 0; h < 8; ++h) {
                float w = w2f[g * 8 + h];
                f32x2 wv = {w, w};
                acc0 += out2[h][0] * wv;
                acc1 += out2[h][1] * wv;
            }
            unsigned u = pack4_bf8(acc0[0], acc0[1], acc1[0], acc1[1]);
            *(unsigned*)(p2b + ((size_t)g * Nn + n) * AST + m0) = u;
        }
    }
}

// ------- PV: obuf[b][n][c] = P2mix(bf8) . v  + b2[g]*colsum_v  (MFMA bf16)
__global__ __launch_bounds__(256) void k_pv_m(
    const unsigned char* __restrict__ p2, const bf16* __restrict__ vt,
    const bf16* __restrict__ b2v, const float* __restrict__ colsum,
    bf16* __restrict__ obuf, int bi0)
{
    __shared__ short ldsA[2048], ldsB[4096];
    const int tid = threadIdx.x;
    const int n0 = blockIdx.x * 64;
    const int z = blockIdx.z, g = z & 7, bloc = z >> 3, b = bi0 + bloc;
    const unsigned char* Ap = p2 + (size_t)(bloc * 8 + g) * Nn * AST;
    const bf16* Bv = vt + ((size_t)b * DHn + g * 128) * AST;
    const int lane = tid & 63;
    const int wm = tid >> 7, wn = (tid >> 6) & 1;
    const int rsub = ((tid >> 6) << 4) | (tid & 15);
    const int q = (tid >> 4) & 3;
    const short8v* A8 = (const short8v*)ldsA;
    const short8v* B8 = (const short8v*)ldsB;
    f32x4 acc[2][4] = {};

    for (int k0 = 0; k0 < AST; k0 += 32) {
        __syncthreads();
        {   // A stage: load 8 bf8 bytes, HW-decode -> bf16 frag slot
            int row = n0 + rsub; row = row < Nn ? row : Nn - 1;
            const unsigned char* src = Ap + (size_t)row * AST + k0 + q * 8;
            unsigned lo = *(const unsigned*)src;
            unsigned hi = *(const unsigned*)(src + 4);
            float d0[4], d1[4];
            unpack4_bf8(lo, d0);
            unpack4_bf8(hi, d1);
            short8v o;
            #pragma unroll
            for (int j = 0; j < 4; ++j) { o[j] = f2s(d0[j]); o[4 + j] = f2s(d1[j]); }
            ((short8v*)ldsA)[((rsub >> 4) * 4 + q) * 16 + (rsub & 15)] = o;
        }
        stage64x32(Bv, 0,  128, k0, AST, AST, ldsB, tid);
        stage64x32(Bv, 64, 128, k0, AST, AST, ldsB + 2048, tid);
        __syncthreads();
        short8v a[2], bb[4];
        #pragma unroll
        for (int i = 0; i < 2; ++i) a[i] = A8[(wm * 2 + i) * 64 + lane];
        #pragma unroll
        for (int j = 0; j < 4; ++j) bb[j] = B8[(wn * 4 + j) * 64 + lane];
        #pragma unroll
        for (int i = 0; i < 2; ++i)
            #pragma unroll
            for (int j = 0; j < 4; ++j)
                acc[i][j] = __builtin_amdgcn_mfma_f32_16x16x32_bf16(a[i], bb[j], acc[i][j], 0, 0, 0);
    }

    bf16* ob = obuf + (size_t)b * Nn * DHn + g * 128;
    const float b2g = b2f(b2v[g]);
    const int rq = lane >> 4, cl = lane & 15;
    #pragma unroll
    for (int i = 0; i < 2; ++i)
        #pragma unroll
        for (int j = 0; j < 4; ++j) {
            int d = (wn * 4 + j) * 16 + cl;
            float cs = b2g * colsum[(size_t)b * DHn + g * 128 + d];
            int nb = n0 + (wm * 2 + i) * 16 + rq * 4;
            #pragma unroll
            for (int r = 0; r < 4; ++r) {
                int n = nb + r;
                if (n < Nn) ob[(size_t)n * DHn + d] = f2b(acc[i][j][r] + cs);
            }
        }
}

// ---- depthwise conv+BN, ADDS into obuf (o += vl), fully vectorized weights
__global__ __launch_bounds__(256) void k_dwconv_add(
    const bf16* __restrict__ vbuf, const bf16* __restrict__ Wvlt,
    const bf16* __restrict__ bvl, const bf16* __restrict__ vls, const bf16* __restrict__ vlb,
    bf16* __restrict__ obuf)
{
    const int t = threadIdx.x;
    const int n = blockIdx.y * 2 + (t >> 7);
    const int bi = blockIdx.z;
    const int c0 = (t & 127) * 8;
    const int h = n / RESn, w = n % RESn;
    float acc[8] = {};
    #pragma unroll
    for (int dh = -1; dh <= 1; ++dh)
        #pragma unroll
        for (int dw = -1; dw <= 1; ++dw) {
            int hh = h + dh, ww = w + dw;
            if (hh < 0 || hh >= RESn || ww < 0 || ww >= RESn) continue;
            int widx = (dh + 1) * 3 + (dw + 1);
            short8v wv = *(const short8v*)&Wvlt[widx * 1024 + c0];
            short8v v  = *(const short8v*)&vbuf[((size_t)bi * Nn + hh * RESn + ww) * DHn + c0];
            #pragma unroll
            for (int u = 0; u < 8; ++u)
                acc[u] += su2f(wv[u]) * su2f(v[u]);
        }
    short8v bv = *(const short8v*)&bvl[c0];
    short8v sv = *(const short8v*)&vls[c0];
    short8v hv = *(const short8v*)&vlb[c0];
    size_t off = ((size_t)bi * Nn + n) * DHn + c0;
    short8v ov = *(short8v*)&obuf[off];
    short8v res;
    #pragma unroll
    for (int u = 0; u < 8; ++u) {
        float vl = su2f(sv[u]) * (acc[u] + su2f(bv[u])) + su2f(hv[u]);
        res[u] = f2s(su2f(ov[u]) + vl);
    }
    *(short8v*)&obuf[off] = res;
}

// --------------------------------------------- output projection + BN (MFMA)
__global__ __launch_bounds__(256) void k_outproj_m(
    const bf16* __restrict__ Wp, const bf16* __restrict__ obuf,
    const bf16* __restrict__ bp, const bf16* __restrict__ ps, const bf16* __restrict__ pb,
    void* __restrict__ outv, const int* __restrict__ flag)
{
    __shared__ short ldsA[2048], ldsB[4096];
    const int n0 = blockIdx.x * 128, oc0 = blockIdx.y * 64;
    const int b = blockIdx.z;
    f32x4 acc[2][4] = {};
    gemm_core<2>(Wp, DHn, 384, oc0,
                 obuf + (size_t)b * Nn * DHn, DHn, Nn, n0,
                 DHn, ldsA, ldsB, acc);
    const int isb = *flag;
    EPI_COORDS(2)
    #pragma unroll
    for (int i = 0; i < 2; ++i)
        #pragma unroll
        for (int j = 0; j < 4; ++j) {
            int n = n0 + (wn * 4 + j) * 16 + cl;
            if (n >= Nn) continue;
            int ocb = oc0 + (wm * 2 + i) * 16 + rq * 4;
            #pragma unroll
            for (int r = 0; r < 4; ++r) {
                int oc = ocb + r;
                float a_ = b2f(ps[oc]);
                float be_ = b2f(bp[oc]) * a_ + b2f(pb[oc]);
                float y = a_ * acc[i][j][r] + be_;
                size_t idx = ((size_t)b * CIN + oc) * Nn + n;
                if (isb) ((bf16*)outv)[idx] = f2b(y);
                else     ((float*)outv)[idx] = y;
            }
        }
}

extern "C" void kernel_launch(void* const* d_in, const int* in_sizes, int n_in,
                              void* d_out, int out_size, void* d_ws, size_t ws_size,
                              hipStream_t stream)
{
    char* ws = (char*)d_ws;
    auto align256 = [](size_t v) { return (v + 255) & ~(size_t)255; };

    size_t off = 0;
    size_t off_flag = off;            off = align256(off + 4);
    size_t p_off[26];
    for (int i = 0; i < 26; ++i) { p_off[i] = off; off = align256(off + (size_t)in_sizes[i] * 2); }
    size_t off_mb   = off; off = align256(off + (size_t)8 * Nn * 4);
    size_t off_ab   = off; off = align256(off + (size_t)8 * Nn * AST * 2);
    size_t off_q    = off; off = align256(off + (size_t)Bn * Nn * 256 * 2);
    size_t off_k    = off; off = align256(off + (size_t)Bn * Nn * 256 * 2);
    size_t off_v    = off; off = align256(off + (size_t)Bn * Nn * DHn * 2);
    size_t off_vt   = off; off = align256(off + (size_t)Bn * DHn * AST * 2);
    size_t off_o    = off; off = align256(off + (size_t)Bn * Nn * DHn * 2);
    size_t off_xt   = off; off = align256(off + (size_t)Bn * Nn * CIN * 2);
    size_t off_wqkv = off; off = align256(off + (size_t)1536 * CIN * 2);
    size_t off_al   = off; off = align256(off + (size_t)1536 * 4);
    size_t off_be   = off; off = align256(off + (size_t)1536 * 4);
    size_t off_wvlt = off; off = align256(off + (size_t)9 * 1024 * 2);
    size_t off_cs   = off; off = align256(off + (size_t)Bn * DHn * 4);
    size_t off_w1f  = off; off = align256(off + 64 * 4);
    size_t off_w2f  = off; off = align256(off + 64 * 4);
    size_t base = off;

    const size_t attn_per_b = (size_t)8 * Nn * AST;      // S bf8
    const size_t p2_per_b   = (size_t)8 * Nn * AST;      // P2 bf8
    int GB = 0;
    const int cand[4] = {8, 4, 2, 1};
    for (int ci = 0; ci < 4; ++ci) {
        if (base + (size_t)cand[ci] * (attn_per_b + p2_per_b) + 512 <= ws_size) { GB = cand[ci]; break; }
    }
    if (!GB) return; // ws too small -> zeros out (diagnostic absmax ~17.4)

    size_t off_attn = base;
    size_t off_p2   = align256(off_attn + (size_t)GB * attn_per_b);

    int*  flag = (int*)(ws + off_flag);
    bf16* Pb[26];
    for (int i = 0; i < 26; ++i) Pb[i] = (bf16*)(ws + p_off[i]);
    float* mb    = (float*)(ws + off_mb);
    bf16* abfull = (bf16*)(ws + off_ab);
    bf16* qbuf  = (bf16*)(ws + off_q);
    bf16* kbuf  = (bf16*)(ws + off_k);
    bf16* vbuf  = (bf16*)(ws + off_v);
    bf16* vt    = (bf16*)(ws + off_vt);
    bf16* obuf  = (bf16*)(ws + off_o);
    bf16* xt    = (bf16*)(ws + off_xt);
    bf16* wqkv  = (bf16*)(ws + off_wqkv);
    float* alf  = (float*)(ws + off_al);
    float* bef  = (float*)(ws + off_be);
    bf16* wvlt  = (bf16*)(ws + off_wvlt);
    float* csum = (float*)(ws + off_cs);
    float* w1f  = (float*)(ws + off_w1f);
    float* w2f  = (float*)(ws + off_w2f);
    unsigned char* attn = (unsigned char*)(ws + off_attn);
    unsigned char* p2b  = (unsigned char*)(ws + off_p2);
    const int* idxs = (const int*)d_in[26];

    k_detect<<<1, 64, 0, stream>>>((const unsigned*)d_in[0], flag);

    PtrArgs pa;
    for (int i = 0; i < 26; ++i) pa.p[i] = d_in[i];
    const int cidx[8] = {14, 15, 16, 20, 21, 22, 23, 24};
    ConvArgs ca;
    for (int i = 0; i < 8; ++i) {
        ca.src[i] = d_in[cidx[i]];
        ca.dstoff[i] = p_off[cidx[i]];
        ca.n[i] = in_sizes[cidx[i]];
    }
    k_prep<<<dim3(288, 13), 256, 0, stream>>>(pa, ca, ws, wqkv, alf, bef, mb, wvlt, w1f, w2f, flag);

    bf16 *bvl = Pb[14], *vls = Pb[15], *vlb = Pb[16],
         *b2v = Pb[20],
         *Wp = Pb[21], *bp = Pb[22], *ps = Pb[23], *pb = Pb[24];

    k_xt_ab<<<dim3(25, 12, 9), 256, 0, stream>>>(d_in[0], xt, mb, idxs, abfull, flag);

    k_proj_m<<<dim3(7, 12, 8), 256, 0, stream>>>(xt, wqkv, alf, bef, qbuf, kbuf, vbuf);
    k_vt_cs<<<dim3(26, 32, 8), 256, 0, stream>>>(vbuf, vt, csum);

    for (int bi0 = 0; bi0 < Bn; bi0 += GB) {
        k_logits_raw<<<dim3(7, 7, GB * 8), 256, 0, stream>>>(qbuf, kbuf, attn, bi0);
        k_softmax_mix<<<dim3(Nn, GB), 256, 0, stream>>>(attn, p2b, abfull, w1f, w2f);
        k_pv_m<<<dim3(13, 1, GB * 8), 256, 0, stream>>>(p2b, vt, b2v, csum, obuf, bi0);
    }

    k_dwconv_add<<<dim3(1, Nn / 2, 8), 256, 0, stream>>>(vbuf, wvlt, bvl, vls, vlb, obuf);
    k_outproj_m<<<dim3(7, 6, 8), 256, 0, stream>>>(Wp, obuf, bp, ps, pb, d_out, flag);
}